// Round 3
// baseline (6306.429 us; speedup 1.0000x reference)
//
#include <hip/hip_runtime.h>

#define LDA 68  // padded leading dim for 64-wide LDS tiles (float4-aligned, bank-spread)

// bf16 helpers (header-free; values are finite, RNE rounding)
__device__ __forceinline__ unsigned short f2bf(float f)
{
    union { float f; unsigned int u; } v; v.f = f;
    unsigned int r = (v.u + 0x7fffu + ((v.u >> 16) & 1u)) >> 16;
    return (unsigned short)r;
}
__device__ __forceinline__ float bf2f(unsigned short b)
{
    union { unsigned int u; float f; } v; v.u = ((unsigned int)b) << 16;
    return v.f;
}

// ---------------------------------------------------------------- utilities

__device__ __forceinline__ void stage_tile(const float* __restrict__ g, int base, int nrows,
                                           float* __restrict__ Ash, int t,
                                           const float* __restrict__ sc, const float* __restrict__ sh)
{
#pragma unroll
    for (int i = 0; i < 4; ++i) {
        int idx = i * 256 + t;
        int r = idx >> 4;
        int c = (idx & 15) << 2;
        float4 v = make_float4(0.f, 0.f, 0.f, 0.f);
        int row = base + r;
        if (row < nrows) v = *(const float4*)(g + (size_t)row * 64 + c);
        if (sc) {
            v.x = v.x * sc[c + 0] + sh[c + 0];
            v.y = v.y * sc[c + 1] + sh[c + 1];
            v.z = v.z * sc[c + 2] + sh[c + 2];
            v.w = v.w * sc[c + 3] + sh[c + 3];
        }
        *(float4*)(Ash + r * LDA + c) = v;
    }
}

__device__ __forceinline__ void stage_w(const float* __restrict__ g, int ldg,
                                        float* __restrict__ Wsh, int t)
{
#pragma unroll
    for (int i = 0; i < 4; ++i) {
        int idx = i * 256 + t;
        int k = idx >> 4;
        int f = (idx & 15) << 2;
        *(float4*)(Wsh + k * 64 + f) = *(const float4*)(g + (size_t)k * ldg + f);
    }
}

// 64x64 GEMM tile: 256 threads, each computes 4 nodes x 4 feats.
__device__ __forceinline__ void gemm_tile(const float* __restrict__ Ash, const float* __restrict__ Wsh,
                                          float acc[4][4], int n0, int f0)
{
#pragma unroll
    for (int k0 = 0; k0 < 64; k0 += 4) {
        float a[4][4], w[4][4];
#pragma unroll
        for (int i = 0; i < 4; ++i) {
            float4 t4 = *(const float4*)(Ash + (n0 + i) * LDA + k0);
            a[i][0] = t4.x; a[i][1] = t4.y; a[i][2] = t4.z; a[i][3] = t4.w;
        }
#pragma unroll
        for (int k = 0; k < 4; ++k) {
            float4 t4 = *(const float4*)(Wsh + (k0 + k) * 64 + f0);
            w[k][0] = t4.x; w[k][1] = t4.y; w[k][2] = t4.z; w[k][3] = t4.w;
        }
#pragma unroll
        for (int i = 0; i < 4; ++i)
#pragma unroll
            for (int k = 0; k < 4; ++k)
#pragma unroll
                for (int j = 0; j < 4; ++j)
                    acc[i][j] = fmaf(a[i][k], w[k][j], acc[i][j]);
    }
}

// ---------------------------------------------------------------- CSR build

__global__ void k_count(const int* __restrict__ dst, int* __restrict__ cnt, int E)
{
    int e = blockIdx.x * 256 + threadIdx.x;
    if (e < E) atomicAdd(&cnt[dst[e]], 1);
}

__global__ void k_scan(const int* __restrict__ cnt, int* __restrict__ rowptr, int n)
{
    __shared__ int part[1024];
    int t = threadIdx.x;
    int C = (n + 1023) >> 10;
    int lo = t * C, hi = min(lo + C, n);
    int s = 0;
    for (int i = lo; i < hi; ++i) s += cnt[i];
    part[t] = s;
    __syncthreads();
    for (int off = 1; off < 1024; off <<= 1) {
        int v = (t >= off) ? part[t - off] : 0;
        __syncthreads();
        part[t] += v;
        __syncthreads();
    }
    int pre = (t == 0) ? 0 : part[t - 1];
    for (int i = lo; i < hi; ++i) { rowptr[i] = pre; pre += cnt[i]; }
    if (t == 1023) rowptr[n] = part[1023];
}

__global__ void k_fill(const int* __restrict__ src, const int* __restrict__ dst,
                       const int* __restrict__ rowptr, int* __restrict__ cursor,
                       int* __restrict__ col, int E)
{
    int e = blockIdx.x * 256 + threadIdx.x;
    if (e < E) {
        int d = dst[e];
        int p = atomicAdd(&cursor[d], 1);
        col[rowptr[d] + p] = src[e];
    }
}

// ---------------------------------------------------------------- BN stats / finalize

__global__ void k_xstats(const float* __restrict__ x, float* __restrict__ stats, int N)
{
    __shared__ float rs[256], rq[256];
    int t = threadIdx.x;
    int f = t & 63, rg = t >> 6;
    float s = 0.f, q = 0.f;
    for (int r = blockIdx.x * 4 + rg; r < N; r += gridDim.x * 4) {
        float v = x[(size_t)r * 64 + f];
        s += v; q += v * v;
    }
    rs[rg * 64 + f] = s; rq[rg * 64 + f] = q;
    __syncthreads();
    if (t < 64) {
        float ts = rs[t] + rs[64 + t] + rs[128 + t] + rs[192 + t];
        float tq = rq[t] + rq[64 + t] + rq[128 + t] + rq[192 + t];
        atomicAdd(&stats[t], ts);
        atomicAdd(&stats[64 + t], tq);
    }
}

__global__ void k_finalize(const float* __restrict__ stats, const float* __restrict__ gamma,
                           const float* __restrict__ beta, float* __restrict__ ss, float invN)
{
    int t = threadIdx.x;
    if (t < 64) {
        float mu = stats[t] * invN;
        float var = stats[64 + t] * invN - mu * mu;
        float rs = rsqrtf(var + 1e-5f);
        float sc = gamma[t] * rs;
        ss[t] = sc;
        ss[64 + t] = beta[t] - mu * sc;
    }
}

// ---------------------------------------------------------------- input proj

__global__ void k_proj(const float* __restrict__ x, const float* __restrict__ ss,
                       const float* __restrict__ W, const float* __restrict__ b,
                       float* __restrict__ h, float* __restrict__ res,
                       unsigned short* __restrict__ hb, int N)
{
    __shared__ __align__(16) float Ash[64 * LDA];
    __shared__ __align__(16) float Wsh[64 * 64];
    int t = threadIdx.x;
    int base = blockIdx.x * 64;
    stage_tile(x, base, N, Ash, t, ss, ss + 64);
    stage_w(W, 64, Wsh, t);
    __syncthreads();
    int n0 = (t >> 4) << 2, f0 = (t & 15) << 2;
    float acc[4][4];
    float4 b4 = *(const float4*)(b + f0);
#pragma unroll
    for (int i = 0; i < 4; ++i) { acc[i][0] = b4.x; acc[i][1] = b4.y; acc[i][2] = b4.z; acc[i][3] = b4.w; }
    gemm_tile(Ash, Wsh, acc, n0, f0);
#pragma unroll
    for (int i = 0; i < 4; ++i) {
        int row = base + n0 + i;
        if (row < N) {
            float4 o = make_float4(fmaxf(acc[i][0], 0.f), fmaxf(acc[i][1], 0.f),
                                   fmaxf(acc[i][2], 0.f), fmaxf(acc[i][3], 0.f));
            *(float4*)(h + (size_t)row * 64 + f0) = o;
            *(float4*)(res + (size_t)row * 64 + f0) = o;
            ushort4 p;
            p.x = f2bf(o.x); p.y = f2bf(o.y); p.z = f2bf(o.z); p.w = f2bf(o.w);
            *(ushort4*)(hb + (size_t)row * 64 + f0) = p;
        }
    }
}

// ---------------------------------------------------------------- tiled GIN aggregation
// Theory: random 256B gathers over a 25.6MB h miss the 4MB per-XCD L2 and ride the
// L2<->LLC fabric (~0.5 TB/s effective, concurrency-insensitive — measured r1/r2).
// Fix: gather from a bf16 mirror (128B rows) in 4 source-range passes of 3.2MB each;
// every XCD keeps the active tile L2-resident. z accumulates across passes with
// nontemporal accesses so streaming traffic doesn't evict the tile.

__global__ void __launch_bounds__(256, 8)
k_aggt(const float* __restrict__ h, const unsigned short* __restrict__ hb,
       const int* __restrict__ rowptr, const int* __restrict__ col,
       float* __restrict__ z, int lo, int hi, int first, int N)
{
    int node = (blockIdx.x << 2) + (threadIdx.x >> 6);
    int lane = threadIdx.x & 63;
    if (node >= N) return;
    int e0 = rowptr[node], e1 = rowptr[node + 1];
    float a = first ? h[(size_t)node * 64 + lane]              // (1+eps)*h_i, eps=0 (exact fp32)
                    : __builtin_nontemporal_load(z + (size_t)node * 64 + lane);
    int e = e0;
    for (; e + 4 <= e1; e += 4) {
        int s0 = col[e + 0], s1 = col[e + 1], s2 = col[e + 2], s3 = col[e + 3];
        if (s0 >= lo && s0 < hi) a += bf2f(hb[(size_t)s0 * 64 + lane]);
        if (s1 >= lo && s1 < hi) a += bf2f(hb[(size_t)s1 * 64 + lane]);
        if (s2 >= lo && s2 < hi) a += bf2f(hb[(size_t)s2 * 64 + lane]);
        if (s3 >= lo && s3 < hi) a += bf2f(hb[(size_t)s3 * 64 + lane]);
    }
    for (; e < e1; ++e) {
        int s = col[e];
        if (s >= lo && s < hi) a += bf2f(hb[(size_t)s * 64 + lane]);
    }
    __builtin_nontemporal_store(a, z + (size_t)node * 64 + lane);
}

// ---------------------------------------------------------------- 3-layer MLP + BN partial stats

__global__ void k_mlp(const float* __restrict__ agg, const float* __restrict__ W3,
                      const float* __restrict__ b3, float* __restrict__ z,
                      float* __restrict__ stats, int N)
{
    __shared__ __align__(16) float Ash[64 * LDA];
    __shared__ __align__(16) float Bsh[64 * LDA];
    __shared__ __align__(16) float Wsh[64 * 64];
    int t = threadIdx.x;
    int base = blockIdx.x * 64;

    stage_tile(agg, base, N, Ash, t, nullptr, nullptr);
    stage_w(W3, 64, Wsh, t);
    __syncthreads();

    int n0 = (t >> 4) << 2, f0 = (t & 15) << 2;
    float acc[4][4];

    // linear 1 + relu
    {
        float4 b4 = *(const float4*)(b3 + f0);
#pragma unroll
        for (int i = 0; i < 4; ++i) { acc[i][0] = b4.x; acc[i][1] = b4.y; acc[i][2] = b4.z; acc[i][3] = b4.w; }
    }
    gemm_tile(Ash, Wsh, acc, n0, f0);
    __syncthreads();
#pragma unroll
    for (int i = 0; i < 4; ++i) {
        float4 o = make_float4(fmaxf(acc[i][0], 0.f), fmaxf(acc[i][1], 0.f),
                               fmaxf(acc[i][2], 0.f), fmaxf(acc[i][3], 0.f));
        *(float4*)(Bsh + (n0 + i) * LDA + f0) = o;
    }
    stage_w(W3 + 64 * 64, 64, Wsh, t);
    __syncthreads();

    // linear 2 + relu
    {
        float4 b4 = *(const float4*)(b3 + 64 + f0);
#pragma unroll
        for (int i = 0; i < 4; ++i) { acc[i][0] = b4.x; acc[i][1] = b4.y; acc[i][2] = b4.z; acc[i][3] = b4.w; }
    }
    gemm_tile(Bsh, Wsh, acc, n0, f0);
    __syncthreads();
#pragma unroll
    for (int i = 0; i < 4; ++i) {
        float4 o = make_float4(fmaxf(acc[i][0], 0.f), fmaxf(acc[i][1], 0.f),
                               fmaxf(acc[i][2], 0.f), fmaxf(acc[i][3], 0.f));
        *(float4*)(Ash + (n0 + i) * LDA + f0) = o;
    }
    stage_w(W3 + 2 * 64 * 64, 64, Wsh, t);
    __syncthreads();

    // linear 3 (no relu; BN follows)
    {
        float4 b4 = *(const float4*)(b3 + 128 + f0);
#pragma unroll
        for (int i = 0; i < 4; ++i) { acc[i][0] = b4.x; acc[i][1] = b4.y; acc[i][2] = b4.z; acc[i][3] = b4.w; }
    }
    gemm_tile(Ash, Wsh, acc, n0, f0);

    // write z + per-block BN partial stats
    float s[4] = {0.f, 0.f, 0.f, 0.f}, q[4] = {0.f, 0.f, 0.f, 0.f};
#pragma unroll
    for (int i = 0; i < 4; ++i) {
        int row = base + n0 + i;
        if (row < N) {
            *(float4*)(z + (size_t)row * 64 + f0) =
                make_float4(acc[i][0], acc[i][1], acc[i][2], acc[i][3]);
#pragma unroll
            for (int j = 0; j < 4; ++j) { s[j] += acc[i][j]; q[j] += acc[i][j] * acc[i][j]; }
        }
    }
    int ng = t >> 4;
#pragma unroll
    for (int j = 0; j < 4; ++j) {
        Bsh[ng * 64 + f0 + j] = s[j];
        Bsh[1024 + ng * 64 + f0 + j] = q[j];
    }
    __syncthreads();
    if (t < 64) {
        float ts = 0.f, tq = 0.f;
#pragma unroll
        for (int g2 = 0; g2 < 16; ++g2) { ts += Bsh[g2 * 64 + t]; tq += Bsh[1024 + g2 * 64 + t]; }
        atomicAdd(&stats[t], ts);
        atomicAdd(&stats[64 + t], tq);
    }
}

// ---------------------------------------------------------------- BN apply + relu (+ residual), maintains bf16 mirror

__global__ void k_bnrelu(const float4* __restrict__ z4, const float* __restrict__ ss,
                         float4* __restrict__ h4, float4* __restrict__ res4,
                         unsigned short* __restrict__ hb, int second, int total4)
{
    int idx = blockIdx.x * 256 + threadIdx.x;
    if (idx >= total4) return;
    int c = (idx & 15) << 2;
    float4 v = z4[idx];
    v.x = fmaxf(v.x * ss[c + 0] + ss[64 + c + 0], 0.f);
    v.y = fmaxf(v.y * ss[c + 1] + ss[64 + c + 1], 0.f);
    v.z = fmaxf(v.z * ss[c + 2] + ss[64 + c + 2], 0.f);
    v.w = fmaxf(v.w * ss[c + 3] + ss[64 + c + 3], 0.f);
    if (second) {
        float4 r = res4[idx];
        v.x += r.x; v.y += r.y; v.z += r.z; v.w += r.w;
        res4[idx] = v;
    }
    h4[idx] = v;
    ushort4 p;
    p.x = f2bf(v.x); p.y = f2bf(v.y); p.z = f2bf(v.z); p.w = f2bf(v.w);
    *(ushort4*)(hb + (size_t)idx * 4) = p;
}

// ---------------------------------------------------------------- attention readout

__global__ void k_wks(const float* __restrict__ Wk, const float* __restrict__ seed,
                      float* __restrict__ wks)
{
    int t = threadIdx.x;  // 256
    int i = t >> 2, hh = t & 3;
    float s = 0.f;
#pragma unroll
    for (int d = 0; d < 16; ++d) s += Wk[i * 64 + hh * 16 + d] * seed[hh * 16 + d];
    wks[i * 4 + hh] = s * 0.25f;  // 1/sqrt(16)
}

__global__ void k_vs(const float* __restrict__ h, const float* __restrict__ Wv,
                     const float* __restrict__ wksg, float* __restrict__ v,
                     float* __restrict__ scores, int N)
{
    __shared__ __align__(16) float Ash[64 * LDA];
    __shared__ __align__(16) float Wsh[64 * 64];
    __shared__ float wk[256];
    int t = threadIdx.x;
    int base = blockIdx.x * 64;
    stage_tile(h, base, N, Ash, t, nullptr, nullptr);
    stage_w(Wv, 64, Wsh, t);
    wk[t] = wksg[t];
    __syncthreads();
    int n0 = (t >> 4) << 2, f0 = (t & 15) << 2;
    float acc[4][4] = {};
    gemm_tile(Ash, Wsh, acc, n0, f0);
#pragma unroll
    for (int i = 0; i < 4; ++i) {
        int row = base + n0 + i;
        if (row < N)
            *(float4*)(v + (size_t)row * 64 + f0) =
                make_float4(acc[i][0], acc[i][1], acc[i][2], acc[i][3]);
    }
    // scores = h @ wk_s  (one thread per (node, head))
    int n = t >> 2, hh = t & 3;
    float s = 0.f;
#pragma unroll
    for (int k0 = 0; k0 < 64; k0 += 4) {
        float4 a = *(const float4*)(Ash + n * LDA + k0);
        s += a.x * wk[(k0 + 0) * 4 + hh];
        s += a.y * wk[(k0 + 1) * 4 + hh];
        s += a.z * wk[(k0 + 2) * 4 + hh];
        s += a.w * wk[(k0 + 3) * 4 + hh];
    }
    int row = base + n;
    if (row < N) scores[(size_t)row * 4 + hh] = s;
}

__global__ void k_bounds(const int* __restrict__ batch, int* __restrict__ gs,
                         int* __restrict__ ge, int N)
{
    int i = blockIdx.x * 256 + threadIdx.x;
    if (i < N) {
        int b = batch[i];
        atomicMin(&gs[b], i);
        atomicMax(&ge[b], i + 1);
    }
}

__global__ void k_pool(const float4* __restrict__ scores4, const float* __restrict__ v,
                       const int* __restrict__ gs, const int* __restrict__ ge,
                       float* __restrict__ pooled, int N)
{
    int g = blockIdx.x;
    int s = gs[g], e = ge[g];
    int t = threadIdx.x;
    __shared__ float4 rmax[256];
    __shared__ float racc[256];
    __shared__ float resum[16];
    if (s >= e) {
        if (t < 64) pooled[g * 64 + t] = 0.f;
        return;
    }
    // phase 1: per-head max
    float4 m = make_float4(-1e30f, -1e30f, -1e30f, -1e30f);
    for (int i = s + t; i < e; i += 256) {
        float4 sc = scores4[i];
        m.x = fmaxf(m.x, sc.x); m.y = fmaxf(m.y, sc.y);
        m.z = fmaxf(m.z, sc.z); m.w = fmaxf(m.w, sc.w);
    }
    rmax[t] = m;
    __syncthreads();
    for (int off = 128; off; off >>= 1) {
        if (t < off) {
            float4 a = rmax[t], b = rmax[t + off];
            a.x = fmaxf(a.x, b.x); a.y = fmaxf(a.y, b.y);
            a.z = fmaxf(a.z, b.z); a.w = fmaxf(a.w, b.w);
            rmax[t] = a;
        }
        __syncthreads();
    }
    float4 smax = rmax[0];
    int rg = t >> 6, f = t & 63, hh = f >> 4;
    float mx = (hh == 0) ? smax.x : ((hh == 1) ? smax.y : ((hh == 2) ? smax.z : smax.w));
    // phase 2: sum e and e*v
    float acc = 0.f, es = 0.f;
    for (int i = s + rg; i < e; i += 4) {
        float4 sc = scores4[i];
        float scl = (hh == 0) ? sc.x : ((hh == 1) ? sc.y : ((hh == 2) ? sc.z : sc.w));
        float ev = __expf(scl - mx);
        acc += ev * v[(size_t)i * 64 + f];
        if ((f & 15) == 0) es += ev;
    }
    racc[rg * 64 + f] = acc;
    if ((f & 15) == 0) resum[rg * 4 + hh] = es;
    __syncthreads();
    if (t < 64) {
        float tot = racc[t] + racc[64 + t] + racc[128 + t] + racc[192 + t];
        int h2 = t >> 4;
        float den = resum[h2] + resum[4 + h2] + resum[8 + h2] + resum[12 + h2];
        pooled[g * 64 + t] = tot / den;
    }
}

__global__ void k_embed(const float* __restrict__ pooled, const float* __restrict__ Wo,
                        float* __restrict__ out, int G)
{
    __shared__ __align__(16) float Ash[64 * LDA];
    __shared__ __align__(16) float Wsh[64 * 64];
    int t = threadIdx.x;
    int base = blockIdx.x * 64;
    stage_tile(pooled, base, G, Ash, t, nullptr, nullptr);
    stage_w(Wo, 64, Wsh, t);
    __syncthreads();
    int n0 = (t >> 4) << 2, f0 = (t & 15) << 2;
    float acc[4][4] = {};
    gemm_tile(Ash, Wsh, acc, n0, f0);
#pragma unroll
    for (int i = 0; i < 4; ++i) {
        int row = base + n0 + i;
        if (row < G)
            *(float4*)(out + (size_t)row * 64 + f0) =
                make_float4(acc[i][0], acc[i][1], acc[i][2], acc[i][3]);
    }
}

__global__ void k_logits(const float* __restrict__ embed, const float* __restrict__ W,
                         const float* __restrict__ b, float* __restrict__ out, int G)
{
    __shared__ __align__(16) float Ash[64 * LDA];
    __shared__ __align__(16) float Wsh[64 * 64];
    int t = threadIdx.x;
    int base = blockIdx.x * 64;
    int co = blockIdx.y * 64;
    stage_tile(embed, base, G, Ash, t, nullptr, nullptr);
    // stage 64x64 slice of [64,128] pred_W
#pragma unroll
    for (int i = 0; i < 4; ++i) {
        int idx = i * 256 + t;
        int k = idx >> 4;
        int f = (idx & 15) << 2;
        *(float4*)(Wsh + k * 64 + f) = *(const float4*)(W + (size_t)k * 128 + co + f);
    }
    __syncthreads();
    int n0 = (t >> 4) << 2, f0 = (t & 15) << 2;
    float acc[4][4];
    float4 b4 = *(const float4*)(b + co + f0);
#pragma unroll
    for (int i = 0; i < 4; ++i) { acc[i][0] = b4.x; acc[i][1] = b4.y; acc[i][2] = b4.z; acc[i][3] = b4.w; }
    gemm_tile(Ash, Wsh, acc, n0, f0);
#pragma unroll
    for (int i = 0; i < 4; ++i) {
        int row = base + n0 + i;
        if (row < G)
            *(float4*)(out + (size_t)row * 128 + co + f0) =
                make_float4(acc[i][0], acc[i][1], acc[i][2], acc[i][3]);
    }
}

// ---------------------------------------------------------------- launch

extern "C" void kernel_launch(void* const* d_in, const int* in_sizes, int n_in,
                              void* d_out, int out_size, void* d_ws, size_t ws_size,
                              hipStream_t stream)
{
    const float* x     = (const float*)d_in[0];
    const int*   eidx  = (const int*)d_in[1];
    const int*   batch = (const int*)d_in[2];
    const float* fn_g  = (const float*)d_in[3];
    const float* fn_b  = (const float*)d_in[4];
    const float* pW    = (const float*)d_in[5];
    const float* pb    = (const float*)d_in[6];
    const float* mlpW  = (const float*)d_in[7];
    const float* mlpb  = (const float*)d_in[8];
    const float* ngm   = (const float*)d_in[9];
    const float* nbt   = (const float*)d_in[10];
    const float* seed  = (const float*)d_in[11];
    const float* Wk    = (const float*)d_in[12];
    const float* Wv    = (const float*)d_in[13];
    const float* Wo    = (const float*)d_in[14];
    const float* predW = (const float*)d_in[15];
    const float* predb = (const float*)d_in[16];

    const int N = 100000, E = 1000000, G = 1000;
    const int* srcv = eidx;
    const int* dstv = eidx + E;

    char* w = (char*)d_ws;
    auto alloc = [&](size_t bytes) {
        char* p = w;
        w += (bytes + 255) & ~(size_t)255;
        return p;
    };
    const size_t NPAD = 100032;  // 1563 * 64
    float*          h      = (float*)alloc(NPAD * 64 * 4);
    float*          res    = (float*)alloc(NPAD * 64 * 4);
    float*          z      = (float*)alloc(NPAD * 64 * 4);   // agg accum / MLP out / v
    unsigned short* hb     = (unsigned short*)alloc(NPAD * 64 * 2);  // bf16 mirror of h
    int*   rowptr = (int*)alloc((size_t)(N + 1) * 4);
    int*   cnt    = (int*)alloc((size_t)N * 4);
    int*   col    = (int*)alloc((size_t)E * 4);
    float* stats  = (float*)alloc(9 * 128 * 4);
    float* ss     = (float*)alloc(9 * 128 * 4);
    float* wks    = (float*)alloc(256 * 4);
    float* scores = (float*)alloc(NPAD * 4 * 4);
    int*   gs     = (int*)alloc((size_t)G * 4);
    int*   ge     = (int*)alloc((size_t)G * 4);
    float* pooled = (float*)alloc((size_t)G * 64 * 4);

    float* emb    = (float*)d_out;            // [G,64]
    float* logits = (float*)d_out + G * 64;   // [G,128]

    const int NB = (N + 63) / 64;  // 1563
    const float invN = 1.f / (float)N;
    const int T = 4, TW = N / T;   // 25000-row source tiles = 3.2 MB bf16 (< 4 MB per-XCD L2)

    // CSR build
    hipMemsetAsync(cnt, 0, (size_t)N * 4, stream);
    hipMemsetAsync(stats, 0, 9 * 128 * 4, stream);
    k_count<<<(E + 255) / 256, 256, 0, stream>>>(dstv, cnt, E);
    k_scan<<<1, 1024, 0, stream>>>(cnt, rowptr, N);
    hipMemsetAsync(cnt, 0, (size_t)N * 4, stream);
    k_fill<<<(E + 255) / 256, 256, 0, stream>>>(srcv, dstv, rowptr, cnt, col, E);

    // feature BN + projection
    k_xstats<<<512, 256, 0, stream>>>(x, stats, N);
    k_finalize<<<1, 64, 0, stream>>>(stats, fn_g, fn_b, ss, invN);
    k_proj<<<NB, 256, 0, stream>>>(x, ss, pW, pb, h, res, hb, N);

    // 4 MPNN blocks x 2 GIN convs
    for (int m = 0; m < 4; ++m)
        for (int c = 0; c < 2; ++c) {
            int sidx = 1 + m * 2 + c;
            for (int t = 0; t < T; ++t)
                k_aggt<<<(N + 3) / 4, 256, 0, stream>>>(h, hb, rowptr, col, z,
                                                        t * TW, (t + 1) * TW, (t == 0) ? 1 : 0, N);
            k_mlp<<<NB, 256, 0, stream>>>(z,
                                          mlpW + (size_t)m * 3 * 64 * 64,
                                          mlpb + (size_t)m * 3 * 64,
                                          z, stats + sidx * 128, N);
            k_finalize<<<1, 64, 0, stream>>>(stats + sidx * 128, ngm + m * 64, nbt + m * 64,
                                             ss + sidx * 128, invN);
            k_bnrelu<<<(N * 16 + 255) / 256, 256, 0, stream>>>(
                (const float4*)z, ss + sidx * 128, (float4*)h, (float4*)res, hb,
                (c == 1) ? 1 : 0, N * 16);
        }

    // attention readout
    k_wks<<<1, 256, 0, stream>>>(Wk, seed, wks);
    k_vs<<<NB, 256, 0, stream>>>(h, Wv, wks, z, scores, N);
    hipMemsetAsync(gs, 0x7f, (size_t)G * 4, stream);
    hipMemsetAsync(ge, 0, (size_t)G * 4, stream);
    k_bounds<<<(N + 255) / 256, 256, 0, stream>>>(batch, gs, ge, N);
    k_pool<<<G, 256, 0, stream>>>((const float4*)scores, z, gs, ge, pooled, N);
    k_embed<<<(G + 63) / 64, 256, 0, stream>>>(pooled, Wo, emb, G);
    dim3 lg((G + 63) / 64, 2);
    k_logits<<<lg, 256, 0, stream>>>(emb, predW, predb, logits, G);
}

// Round 4
// 1413.999 us; speedup vs baseline: 4.4600x; 4.4600x over previous
//
#include <hip/hip_runtime.h>

#define LDA 68  // padded leading dim for 64-wide fp32 LDS tiles (small VALU GEMMs only)

typedef __attribute__((ext_vector_type(8))) short bf16x8;
typedef __attribute__((ext_vector_type(4))) float floatx4;

// bf16 helpers (RNE)
__device__ __forceinline__ unsigned short f2bf(float f)
{
    union { float f; unsigned int u; } v; v.f = f;
    unsigned int r = (v.u + 0x7fffu + ((v.u >> 16) & 1u)) >> 16;
    return (unsigned short)r;
}
__device__ __forceinline__ float bf2f(unsigned short b)
{
    union { unsigned int u; float f; } v; v.u = ((unsigned int)b) << 16;
    return v.f;
}

// acc += (Ah+Al) * (Bh+Bl), dropping Al*Bl  (~16-bit-mantissa GEMM)
#define MFMA3(accv, ah, al, bh, bl)                                              \
    accv = __builtin_amdgcn_mfma_f32_16x16x32_bf16(ah, bh, accv, 0, 0, 0);       \
    accv = __builtin_amdgcn_mfma_f32_16x16x32_bf16(al, bh, accv, 0, 0, 0);       \
    accv = __builtin_amdgcn_mfma_f32_16x16x32_bf16(ah, bl, accv, 0, 0, 0);

__device__ __forceinline__ void pack_pair(const float* f, bf16x8& hi, bf16x8& lo)
{
#pragma unroll
    for (int j = 0; j < 8; ++j) {
        unsigned short hb = f2bf(f[j]);
        hi[j] = (short)hb;
        lo[j] = (short)f2bf(f[j] - bf2f(hb));
    }
}

// stage fp32 W[64k][64n] -> LDS bf16 hi/lo, transposed+padded [n][72k] (B-frag friendly)
__device__ __forceinline__ void stage_wpair(const float* __restrict__ Wg,
                                            short* __restrict__ Wh, short* __restrict__ Wl, int t)
{
#pragma unroll
    for (int i = 0; i < 16; ++i) {
        int idx = i * 256 + t;
        int k = idx >> 6, n = idx & 63;
        float w = Wg[k * 64 + n];
        unsigned short hb = f2bf(w);
        Wh[n * 72 + k] = (short)hb;
        Wl[n * 72 + k] = (short)f2bf(w - bf2f(hb));
    }
}

// ---------------------------------------------------------------- small VALU GEMM helpers (k_embed/k_logits only)

__device__ __forceinline__ void stage_tile(const float* __restrict__ g, int base, int nrows,
                                           float* __restrict__ Ash, int t)
{
#pragma unroll
    for (int i = 0; i < 4; ++i) {
        int idx = i * 256 + t;
        int r = idx >> 4;
        int c = (idx & 15) << 2;
        float4 v = make_float4(0.f, 0.f, 0.f, 0.f);
        int row = base + r;
        if (row < nrows) v = *(const float4*)(g + (size_t)row * 64 + c);
        *(float4*)(Ash + r * LDA + c) = v;
    }
}

__device__ __forceinline__ void stage_w(const float* __restrict__ g, int ldg,
                                        float* __restrict__ Wsh, int t)
{
#pragma unroll
    for (int i = 0; i < 4; ++i) {
        int idx = i * 256 + t;
        int k = idx >> 4;
        int f = (idx & 15) << 2;
        *(float4*)(Wsh + k * 64 + f) = *(const float4*)(g + (size_t)k * ldg + f);
    }
}

__device__ __forceinline__ void gemm_tile(const float* __restrict__ Ash, const float* __restrict__ Wsh,
                                          float acc[4][4], int n0, int f0)
{
#pragma unroll
    for (int k0 = 0; k0 < 64; k0 += 4) {
        float a[4][4], w[4][4];
#pragma unroll
        for (int i = 0; i < 4; ++i) {
            float4 t4 = *(const float4*)(Ash + (n0 + i) * LDA + k0);
            a[i][0] = t4.x; a[i][1] = t4.y; a[i][2] = t4.z; a[i][3] = t4.w;
        }
#pragma unroll
        for (int k = 0; k < 4; ++k) {
            float4 t4 = *(const float4*)(Wsh + (k0 + k) * 64 + f0);
            w[k][0] = t4.x; w[k][1] = t4.y; w[k][2] = t4.z; w[k][3] = t4.w;
        }
#pragma unroll
        for (int i = 0; i < 4; ++i)
#pragma unroll
            for (int k = 0; k < 4; ++k)
#pragma unroll
                for (int j = 0; j < 4; ++j)
                    acc[i][j] = fmaf(a[i][k], w[k][j], acc[i][j]);
    }
}

// ---------------------------------------------------------------- CSR build

__global__ void k_count(const int* __restrict__ dst, int* __restrict__ cnt, int E)
{
    for (int e = blockIdx.x * 256 + threadIdx.x; e < E; e += gridDim.x * 256)
        atomicAdd(&cnt[dst[e]], 1);
}

__global__ void k_scan(const int* __restrict__ cnt, int* __restrict__ rowptr, int n)
{
    __shared__ int part[1024];
    int t = threadIdx.x;
    int C = (n + 1023) >> 10;
    int lo = t * C, hi = min(lo + C, n);
    int s = 0;
    for (int i = lo; i < hi; ++i) s += cnt[i];
    part[t] = s;
    __syncthreads();
    for (int off = 1; off < 1024; off <<= 1) {
        int v = (t >= off) ? part[t - off] : 0;
        __syncthreads();
        part[t] += v;
        __syncthreads();
    }
    int pre = (t == 0) ? 0 : part[t - 1];
    for (int i = lo; i < hi; ++i) { rowptr[i] = pre; pre += cnt[i]; }
    if (t == 1023) rowptr[n] = part[1023];
}

__global__ void k_fill(const int* __restrict__ src, const int* __restrict__ dst,
                       const int* __restrict__ rowptr, int* __restrict__ cursor,
                       int* __restrict__ col, int E)
{
    for (int e = blockIdx.x * 256 + threadIdx.x; e < E; e += gridDim.x * 256) {
        int d = dst[e];
        int p = atomicAdd(&cursor[d], 1);
        col[rowptr[d] + p] = src[e];
    }
}

// ---------------------------------------------------------------- BN stats / finalize (4-way replicated atomics)

__global__ void k_xstats(const float* __restrict__ x, float* __restrict__ stats, int N)
{
    __shared__ float rs[256], rq[256];
    int t = threadIdx.x;
    int f = t & 63, rg = t >> 6;
    float s = 0.f, q = 0.f;
    for (int r = blockIdx.x * 4 + rg; r < N; r += gridDim.x * 4) {
        float v = x[(size_t)r * 64 + f];
        s += v; q += v * v;
    }
    rs[rg * 64 + f] = s; rq[rg * 64 + f] = q;
    __syncthreads();
    if (t < 64) {
        float ts = rs[t] + rs[64 + t] + rs[128 + t] + rs[192 + t];
        float tq = rq[t] + rq[64 + t] + rq[128 + t] + rq[192 + t];
        int rep = (blockIdx.x & 3) * 128;
        atomicAdd(&stats[rep + t], ts);
        atomicAdd(&stats[rep + 64 + t], tq);
    }
}

__global__ void k_finalize(const float* __restrict__ stats, const float* __restrict__ gamma,
                           const float* __restrict__ beta, float* __restrict__ ss, float invN)
{
    int t = threadIdx.x;
    if (t < 64) {
        float su = stats[t] + stats[128 + t] + stats[256 + t] + stats[384 + t];
        float qu = stats[64 + t] + stats[192 + t] + stats[320 + t] + stats[448 + t];
        float mu = su * invN;
        float var = qu * invN - mu * mu;
        float rs = rsqrtf(var + 1e-5f);
        float sc = gamma[t] * rs;
        ss[t] = sc;
        ss[64 + t] = beta[t] - mu * sc;
    }
}

// ---------------------------------------------------------------- input projection (MFMA)

__global__ void __launch_bounds__(256, 4)
k_proj(const float* __restrict__ x, const float* __restrict__ ssArr,
       const float* __restrict__ W, const float* __restrict__ b,
       float* __restrict__ h, float* __restrict__ res,
       unsigned short* __restrict__ hbh, unsigned short* __restrict__ hbl, int N)
{
    __shared__ short Wh[64 * 72], Wl[64 * 72];
    __shared__ float ScSh[128];
    __shared__ float BiasSh[64];
    int t = threadIdx.x;
    int wave = t >> 6, lane = t & 63;
    int m = lane & 15, qd = lane >> 4;
    int base = blockIdx.x * 64;
    int nodeA = base + wave * 16 + m;

    if (t < 128) ScSh[t] = ssArr[t];
    if (t < 64) BiasSh[t] = b[t];
    stage_wpair(W, Wh, Wl, t);
    __syncthreads();

    // A frags: normed x rows (clamped tail to stay in-bounds; garbage rows masked at store)
    int rowc = min(nodeA, N - 1);
    bf16x8 ah[2], al[2];
#pragma unroll
    for (int kc = 0; kc < 2; ++kc) {
        floatx4 x0 = *(const floatx4*)(x + (size_t)rowc * 64 + kc * 32 + qd * 8);
        floatx4 x1 = *(const floatx4*)(x + (size_t)rowc * 64 + kc * 32 + qd * 8 + 4);
        float av[8];
#pragma unroll
        for (int j = 0; j < 8; ++j) {
            int k = kc * 32 + qd * 8 + j;
            float xv = (j < 4) ? x0[j] : x1[j - 4];
            av[j] = xv * ScSh[k] + ScSh[64 + k];
        }
        pack_pair(av, ah[kc], al[kc]);
    }

    floatx4 acc[4];
#pragma unroll
    for (int tt = 0; tt < 4; ++tt) {
        float bv = BiasSh[tt * 16 + m];
        acc[tt] = (floatx4){bv, bv, bv, bv};
    }
#pragma unroll
    for (int kc = 0; kc < 2; ++kc)
#pragma unroll
        for (int tt = 0; tt < 4; ++tt) {
            bf16x8 bh = *(const bf16x8*)(Wh + (tt * 16 + m) * 72 + kc * 32 + qd * 8);
            bf16x8 bl = *(const bf16x8*)(Wl + (tt * 16 + m) * 72 + kc * 32 + qd * 8);
            MFMA3(acc[tt], ah[kc], al[kc], bh, bl);
        }

#pragma unroll
    for (int tt = 0; tt < 4; ++tt)
#pragma unroll
        for (int r = 0; r < 4; ++r) {
            int node = base + wave * 16 + qd * 4 + r;
            if (node < N) {
                int col = tt * 16 + m;
                float v = fmaxf(acc[tt][r], 0.f);
                h[(size_t)node * 64 + col] = v;
                res[(size_t)node * 64 + col] = v;
                unsigned short hb = f2bf(v);
                hbh[(size_t)node * 64 + col] = hb;
                hbl[(size_t)node * 64 + col] = f2bf(v - bf2f(hb));
            }
        }
}

// ---------------------------------------------------------------- GIN aggregation: persistent waves, bf16 gather

__global__ void __launch_bounds__(256, 8)
k_agg(const float* __restrict__ h, const unsigned short* __restrict__ hbh,
      const int* __restrict__ rowptr, const int* __restrict__ col,
      unsigned short* __restrict__ zh, unsigned short* __restrict__ zl, int N)
{
    int wid = blockIdx.x * 4 + (threadIdx.x >> 6);
    int lane = threadIdx.x & 63;
    int tot = gridDim.x * 4;
    for (int node = wid; node < N; node += tot) {
        float a = h[(size_t)node * 64 + lane];  // (1+eps)*h_i, eps=0, exact fp32
        int e0 = rowptr[node], e1 = rowptr[node + 1];
        int e = e0;
        for (; e + 8 <= e1; e += 8) {
            int s0 = col[e + 0], s1 = col[e + 1], s2 = col[e + 2], s3 = col[e + 3];
            int s4 = col[e + 4], s5 = col[e + 5], s6 = col[e + 6], s7 = col[e + 7];
            float v0 = bf2f(hbh[(size_t)s0 * 64 + lane]);
            float v1 = bf2f(hbh[(size_t)s1 * 64 + lane]);
            float v2 = bf2f(hbh[(size_t)s2 * 64 + lane]);
            float v3 = bf2f(hbh[(size_t)s3 * 64 + lane]);
            float v4 = bf2f(hbh[(size_t)s4 * 64 + lane]);
            float v5 = bf2f(hbh[(size_t)s5 * 64 + lane]);
            float v6 = bf2f(hbh[(size_t)s6 * 64 + lane]);
            float v7 = bf2f(hbh[(size_t)s7 * 64 + lane]);
            a += ((v0 + v1) + (v2 + v3)) + ((v4 + v5) + (v6 + v7));
        }
        if (e + 4 <= e1) {
            int s0 = col[e + 0], s1 = col[e + 1], s2 = col[e + 2], s3 = col[e + 3];
            a += (bf2f(hbh[(size_t)s0 * 64 + lane]) + bf2f(hbh[(size_t)s1 * 64 + lane]))
               + (bf2f(hbh[(size_t)s2 * 64 + lane]) + bf2f(hbh[(size_t)s3 * 64 + lane]));
            e += 4;
        }
        if (e + 2 <= e1) {
            a += bf2f(hbh[(size_t)col[e] * 64 + lane]) + bf2f(hbh[(size_t)col[e + 1] * 64 + lane]);
            e += 2;
        }
        if (e < e1) a += bf2f(hbh[(size_t)col[e] * 64 + lane]);
        unsigned short hb = f2bf(a);
        zh[(size_t)node * 64 + lane] = hb;
        zl[(size_t)node * 64 + lane] = f2bf(a - bf2f(hb));
    }
}

// ---------------------------------------------------------------- 3-layer MLP (MFMA, bf16-pair) + BN partial stats
// zh/zl are A-input (from k_agg) and C3-output (in-place; each block touches only its own rows).

__global__ void __launch_bounds__(256, 4)
k_mlp(unsigned short* __restrict__ zh, unsigned short* __restrict__ zl,
      const float* __restrict__ W3, const float* __restrict__ b3,
      float* __restrict__ stats, int N)
{
    __shared__ short Wh[64 * 72], Wl[64 * 72];
    __shared__ float Aint[4 * 16 * 68];
    __shared__ float BiasSh[192];
    int t = threadIdx.x;
    int wave = t >> 6, lane = t & 63;
    int m = lane & 15, qd = lane >> 4;
    int base = blockIdx.x * 64;
    int nodeA = base + wave * 16 + m;
    float* Aw = Aint + wave * 1088;

    if (t < 192) BiasSh[t] = b3[t];
    stage_wpair(W3, Wh, Wl, t);

    // A1 frags from global bf16 pairs (rows >= N read padded-poison; masked at stores/stats)
    bf16x8 a1h[2], a1l[2];
#pragma unroll
    for (int kc = 0; kc < 2; ++kc) {
        a1h[kc] = *(const bf16x8*)(zh + (size_t)nodeA * 64 + kc * 32 + qd * 8);
        a1l[kc] = *(const bf16x8*)(zl + (size_t)nodeA * 64 + kc * 32 + qd * 8);
    }
    __syncthreads();

    floatx4 acc[4];

    // -------- linear 1 + relu
#pragma unroll
    for (int tt = 0; tt < 4; ++tt) {
        float bv = BiasSh[tt * 16 + m];
        acc[tt] = (floatx4){bv, bv, bv, bv};
    }
#pragma unroll
    for (int kc = 0; kc < 2; ++kc)
#pragma unroll
        for (int tt = 0; tt < 4; ++tt) {
            bf16x8 bh = *(const bf16x8*)(Wh + (tt * 16 + m) * 72 + kc * 32 + qd * 8);
            bf16x8 bl = *(const bf16x8*)(Wl + (tt * 16 + m) * 72 + kc * 32 + qd * 8);
            MFMA3(acc[tt], a1h[kc], a1l[kc], bh, bl);
        }
#pragma unroll
    for (int tt = 0; tt < 4; ++tt)
#pragma unroll
        for (int r = 0; r < 4; ++r)
            Aw[(qd * 4 + r) * 68 + tt * 16 + m] = fmaxf(acc[tt][r], 0.f);
    __syncthreads();
    stage_wpair(W3 + 4096, Wh, Wl, t);
    __syncthreads();

    // -------- linear 2 + relu (A from Aint, transposed to A-layout)
#pragma unroll
    for (int tt = 0; tt < 4; ++tt) {
        float bv = BiasSh[64 + tt * 16 + m];
        acc[tt] = (floatx4){bv, bv, bv, bv};
    }
#pragma unroll
    for (int kc = 0; kc < 2; ++kc) {
        floatx4 x0 = *(const floatx4*)(Aw + m * 68 + kc * 32 + qd * 8);
        floatx4 x1 = *(const floatx4*)(Aw + m * 68 + kc * 32 + qd * 8 + 4);
        float av[8];
#pragma unroll
        for (int j = 0; j < 8; ++j) av[j] = (j < 4) ? x0[j] : x1[j - 4];
        bf16x8 ah, al;
        pack_pair(av, ah, al);
#pragma unroll
        for (int tt = 0; tt < 4; ++tt) {
            bf16x8 bh = *(const bf16x8*)(Wh + (tt * 16 + m) * 72 + kc * 32 + qd * 8);
            bf16x8 bl = *(const bf16x8*)(Wl + (tt * 16 + m) * 72 + kc * 32 + qd * 8);
            MFMA3(acc[tt], ah, al, bh, bl);
        }
    }
#pragma unroll
    for (int tt = 0; tt < 4; ++tt)
#pragma unroll
        for (int r = 0; r < 4; ++r)
            Aw[(qd * 4 + r) * 68 + tt * 16 + m] = fmaxf(acc[tt][r], 0.f);
    __syncthreads();
    stage_wpair(W3 + 8192, Wh, Wl, t);
    __syncthreads();

    // -------- linear 3 (no relu)
#pragma unroll
    for (int tt = 0; tt < 4; ++tt) {
        float bv = BiasSh[128 + tt * 16 + m];
        acc[tt] = (floatx4){bv, bv, bv, bv};
    }
#pragma unroll
    for (int kc = 0; kc < 2; ++kc) {
        floatx4 x0 = *(const floatx4*)(Aw + m * 68 + kc * 32 + qd * 8);
        floatx4 x1 = *(const floatx4*)(Aw + m * 68 + kc * 32 + qd * 8 + 4);
        float av[8];
#pragma unroll
        for (int j = 0; j < 8; ++j) av[j] = (j < 4) ? x0[j] : x1[j - 4];
        bf16x8 ah, al;
        pack_pair(av, ah, al);
#pragma unroll
        for (int tt = 0; tt < 4; ++tt) {
            bf16x8 bh = *(const bf16x8*)(Wh + (tt * 16 + m) * 72 + kc * 32 + qd * 8);
            bf16x8 bl = *(const bf16x8*)(Wl + (tt * 16 + m) * 72 + kc * 32 + qd * 8);
            MFMA3(acc[tt], ah, al, bh, bl);
        }
    }

    // store z as bf16 pair (pre-BN) + BN partial stats from fp32 accumulators
#pragma unroll
    for (int tt = 0; tt < 4; ++tt)
#pragma unroll
        for (int r = 0; r < 4; ++r) {
            int node = base + wave * 16 + qd * 4 + r;
            if (node < N) {
                int colg = tt * 16 + m;
                float v = acc[tt][r];
                unsigned short hb = f2bf(v);
                zh[(size_t)node * 64 + colg] = hb;
                zl[(size_t)node * 64 + colg] = f2bf(v - bf2f(hb));
            }
        }
    __syncthreads();  // all Wh B-frag reads done; reuse Wh as fp32 stats scratch
    float* SW = (float*)Wh;  // 4096 floats
#pragma unroll
    for (int tt = 0; tt < 4; ++tt) {
        float s = 0.f, q = 0.f;
#pragma unroll
        for (int r = 0; r < 4; ++r) {
            int node = base + wave * 16 + qd * 4 + r;
            float v = (node < N) ? acc[tt][r] : 0.f;
            s += v; q += v * v;
        }
        SW[(tt * 16 + m) * 16 + wave * 4 + qd] = s;
        SW[2048 + (tt * 16 + m) * 16 + wave * 4 + qd] = q;
    }
    __syncthreads();
    if (t < 64) {
        float s = 0.f, q = 0.f;
#pragma unroll
        for (int i = 0; i < 16; ++i) { s += SW[t * 16 + i]; q += SW[2048 + t * 16 + i]; }
        int rep = (blockIdx.x & 3) * 128;
        atomicAdd(&stats[rep + t], s);
        atomicAdd(&stats[rep + 64 + t], q);
    }
}

// ---------------------------------------------------------------- BN apply + relu (+ residual), writes h + bf16-pair mirror

__global__ void k_bnrelu(const ushort4* __restrict__ zh4, const ushort4* __restrict__ zl4,
                         const float* __restrict__ ss,
                         float4* __restrict__ h4, float4* __restrict__ res4,
                         ushort4* __restrict__ hbh4, ushort4* __restrict__ hbl4,
                         int second, int total4)
{
    for (int idx = blockIdx.x * 256 + threadIdx.x; idx < total4; idx += gridDim.x * 256) {
        int c = (idx & 15) << 2;
        ushort4 zh = zh4[idx], zl = zl4[idx];
        float4 v;
        v.x = bf2f(zh.x) + bf2f(zl.x);
        v.y = bf2f(zh.y) + bf2f(zl.y);
        v.z = bf2f(zh.z) + bf2f(zl.z);
        v.w = bf2f(zh.w) + bf2f(zl.w);
        v.x = fmaxf(v.x * ss[c + 0] + ss[64 + c + 0], 0.f);
        v.y = fmaxf(v.y * ss[c + 1] + ss[64 + c + 1], 0.f);
        v.z = fmaxf(v.z * ss[c + 2] + ss[64 + c + 2], 0.f);
        v.w = fmaxf(v.w * ss[c + 3] + ss[64 + c + 3], 0.f);
        if (second) {
            float4 r = res4[idx];
            v.x += r.x; v.y += r.y; v.z += r.z; v.w += r.w;
            res4[idx] = v;
        }
        h4[idx] = v;
        ushort4 ph, pl;
        ph.x = f2bf(v.x); pl.x = f2bf(v.x - bf2f(ph.x));
        ph.y = f2bf(v.y); pl.y = f2bf(v.y - bf2f(ph.y));
        ph.z = f2bf(v.z); pl.z = f2bf(v.z - bf2f(ph.z));
        ph.w = f2bf(v.w); pl.w = f2bf(v.w - bf2f(ph.w));
        hbh4[idx] = ph; hbl4[idx] = pl;
    }
}

// ---------------------------------------------------------------- attention readout

__global__ void k_wks(const float* __restrict__ Wk, const float* __restrict__ seed,
                      float* __restrict__ wks)
{
    int t = threadIdx.x;  // 256
    int i = t >> 2, hh = t & 3;
    float s = 0.f;
#pragma unroll
    for (int d = 0; d < 16; ++d) s += Wk[i * 64 + hh * 16 + d] * seed[hh * 16 + d];
    wks[i * 4 + hh] = s * 0.25f;  // 1/sqrt(16)
}

// v = h @ Wv (MFMA, pair) and scores = h @ wks (extra 16-wide tile, cols 0-3 live)
__global__ void __launch_bounds__(256, 4)
k_vs(const unsigned short* __restrict__ hbh, const unsigned short* __restrict__ hbl,
     const float* __restrict__ Wv, const float* __restrict__ wksg,
     float* __restrict__ v, float* __restrict__ scores, int N)
{
    __shared__ short Wh[64 * 72], Wl[64 * 72];
    __shared__ short Sh[16 * 72], Sl[16 * 72];
    int t = threadIdx.x;
    int wave = t >> 6, lane = t & 63;
    int m = lane & 15, qd = lane >> 4;
    int base = blockIdx.x * 64;
    int nodeA = base + wave * 16 + m;

    stage_wpair(Wv, Wh, Wl, t);
#pragma unroll
    for (int i = 0; i < 4; ++i) {
        int idx = i * 256 + t;
        int k = idx >> 4, n = idx & 15;
        float wv = (n < 4) ? wksg[k * 4 + n] : 0.f;
        unsigned short hb = f2bf(wv);
        Sh[n * 72 + k] = (short)hb;
        Sl[n * 72 + k] = (short)f2bf(wv - bf2f(hb));
    }

    bf16x8 ah[2], al[2];
#pragma unroll
    for (int kc = 0; kc < 2; ++kc) {
        ah[kc] = *(const bf16x8*)(hbh + (size_t)nodeA * 64 + kc * 32 + qd * 8);
        al[kc] = *(const bf16x8*)(hbl + (size_t)nodeA * 64 + kc * 32 + qd * 8);
    }
    __syncthreads();

    floatx4 acc[5] = {};
#pragma unroll
    for (int kc = 0; kc < 2; ++kc) {
#pragma unroll
        for (int tt = 0; tt < 4; ++tt) {
            bf16x8 bh = *(const bf16x8*)(Wh + (tt * 16 + m) * 72 + kc * 32 + qd * 8);
            bf16x8 bl = *(const bf16x8*)(Wl + (tt * 16 + m) * 72 + kc * 32 + qd * 8);
            MFMA3(acc[tt], ah[kc], al[kc], bh, bl);
        }
        bf16x8 sh = *(const bf16x8*)(Sh + m * 72 + kc * 32 + qd * 8);
        bf16x8 sl = *(const bf16x8*)(Sl + m * 72 + kc * 32 + qd * 8);
        MFMA3(acc[4], ah[kc], al[kc], sh, sl);
    }

#pragma unroll
    for (int tt = 0; tt < 4; ++tt)
#pragma unroll
        for (int r = 0; r < 4; ++r) {
            int node = base + wave * 16 + qd * 4 + r;
            if (node < N)
                v[(size_t)node * 64 + tt * 16 + m] = acc[tt][r];
        }
    if (m < 4) {
#pragma unroll
        for (int r = 0; r < 4; ++r) {
            int node = base + wave * 16 + qd * 4 + r;
            if (node < N) scores[(size_t)node * 4 + m] = acc[4][r];
        }
    }
}

__global__ void k_bounds(const int* __restrict__ batch, int* __restrict__ gs,
                         int* __restrict__ ge, int N)
{
    for (int i = blockIdx.x * 256 + threadIdx.x; i < N; i += gridDim.x * 256) {
        int b = batch[i];
        atomicMin(&gs[b], i);
        atomicMax(&ge[b], i + 1);
    }
}

__global__ void k_pool(const float4* __restrict__ scores4, const float* __restrict__ v,
                       const int* __restrict__ gs, const int* __restrict__ ge,
                       float* __restrict__ pooled, int N)
{
    int g = blockIdx.x;
    int s = gs[g], e = ge[g];
    int t = threadIdx.x;
    __shared__ float4 rmax[256];
    __shared__ float racc[256];
    __shared__ float resum[16];
    if (s >= e) {
        if (t < 64) pooled[g * 64 + t] = 0.f;
        return;
    }
    float4 m = make_float4(-1e30f, -1e30f, -1e30f, -1e30f);
    for (int i = s + t; i < e; i += 256) {
        float4 sc = scores4[i];
        m.x = fmaxf(m.x, sc.x); m.y = fmaxf(m.y, sc.y);
        m.z = fmaxf(m.z, sc.z); m.w = fmaxf(m.w, sc.w);
    }
    rmax[t] = m;
    __syncthreads();
    for (int off = 128; off; off >>= 1) {
        if (t < off) {
            float4 a = rmax[t], b = rmax[t + off];
            a.x = fmaxf(a.x, b.x); a.y = fmaxf(a.y, b.y);
            a.z = fmaxf(a.z, b.z); a.w = fmaxf(a.w, b.w);
            rmax[t] = a;
        }
        __syncthreads();
    }
    float4 smax = rmax[0];
    int rg = t >> 6, f = t & 63, hh = f >> 4;
    float mx = (hh == 0) ? smax.x : ((hh == 1) ? smax.y : ((hh == 2) ? smax.z : smax.w));
    float acc = 0.f, es = 0.f;
    for (int i = s + rg; i < e; i += 4) {
        float4 sc = scores4[i];
        float scl = (hh == 0) ? sc.x : ((hh == 1) ? sc.y : ((hh == 2) ? sc.z : sc.w));
        float ev = __expf(scl - mx);
        acc += ev * v[(size_t)i * 64 + f];
        if ((f & 15) == 0) es += ev;
    }
    racc[rg * 64 + f] = acc;
    if ((f & 15) == 0) resum[rg * 4 + hh] = es;
    __syncthreads();
    if (t < 64) {
        float tot = racc[t] + racc[64 + t] + racc[128 + t] + racc[192 + t];
        int h2 = t >> 4;
        float den = resum[h2] + resum[4 + h2] + resum[8 + h2] + resum[12 + h2];
        pooled[g * 64 + t] = tot / den;
    }
}

__global__ void k_embed(const float* __restrict__ pooled, const float* __restrict__ Wo,
                        float* __restrict__ out, int G)
{
    __shared__ __align__(16) float Ash[64 * LDA];
    __shared__ __align__(16) float Wsh[64 * 64];
    int t = threadIdx.x;
    int base = blockIdx.x * 64;
    stage_tile(pooled, base, G, Ash, t);
    stage_w(Wo, 64, Wsh, t);
    __syncthreads();
    int n0 = (t >> 4) << 2, f0 = (t & 15) << 2;
    float acc[4][4] = {};
    gemm_tile(Ash, Wsh, acc, n0, f0);
#pragma unroll
    for (int i = 0; i < 4; ++i) {
        int row = base + n0 + i;
        if (row < G)
            *(float4*)(out + (size_t)row * 64 + f0) =
                make_float4(acc[i][0], acc[i][1], acc[i][2], acc[i][3]);
    }
}

__global__ void k_logits(const float* __restrict__ embed, const float* __restrict__ W,
                         const float* __restrict__ b, float* __restrict__ out, int G)
{
    __shared__ __align__(16) float Ash[64 * LDA];
    __shared__ __align__(16) float Wsh[64 * 64];
    int t = threadIdx.x;
    int base = blockIdx.x * 64;
    int co = blockIdx.y * 64;
    stage_tile(embed, base, G, Ash, t);
#pragma unroll
    for (int i = 0; i < 4; ++i) {
        int idx = i * 256 + t;
        int k = idx >> 4;
        int f = (idx & 15) << 2;
        *(float4*)(Wsh + k * 64 + f) = *(const float4*)(W + (size_t)k * 128 + co + f);
    }
    __syncthreads();
    int n0 = (t >> 4) << 2, f0 = (t & 15) << 2;
    float acc[4][4];
    float4 b4 = *(const float4*)(b + co + f0);
#pragma unroll
    for (int i = 0; i < 4; ++i) { acc[i][0] = b4.x; acc[i][1] = b4.y; acc[i][2] = b4.z; acc[i][3] = b4.w; }
    gemm_tile(Ash, Wsh, acc, n0, f0);
#pragma unroll
    for (int i = 0; i < 4; ++i) {
        int row = base + n0 + i;
        if (row < G)
            *(float4*)(out + (size_t)row * 128 + co + f0) =
                make_float4(acc[i][0], acc[i][1], acc[i][2], acc[i][3]);
    }
}

// ---------------------------------------------------------------- launch

extern "C" void kernel_launch(void* const* d_in, const int* in_sizes, int n_in,
                              void* d_out, int out_size, void* d_ws, size_t ws_size,
                              hipStream_t stream)
{
    const float* x     = (const float*)d_in[0];
    const int*   eidx  = (const int*)d_in[1];
    const int*   batch = (const int*)d_in[2];
    const float* fn_g  = (const float*)d_in[3];
    const float* fn_b  = (const float*)d_in[4];
    const float* pW    = (const float*)d_in[5];
    const float* pb    = (const float*)d_in[6];
    const float* mlpW  = (const float*)d_in[7];
    const float* mlpb  = (const float*)d_in[8];
    const float* ngm   = (const float*)d_in[9];
    const float* nbt   = (const float*)d_in[10];
    const float* seed  = (const float*)d_in[11];
    const float* Wk    = (const float*)d_in[12];
    const float* Wv    = (const float*)d_in[13];
    const float* Wo    = (const float*)d_in[14];
    const float* predW = (const float*)d_in[15];
    const float* predb = (const float*)d_in[16];

    const int N = 100000, E = 1000000, G = 1000;
    const int* srcv = eidx;
    const int* dstv = eidx + E;

    char* w = (char*)d_ws;
    auto alloc = [&](size_t bytes) {
        char* p = w;
        w += (bytes + 255) & ~(size_t)255;
        return p;
    };
    const size_t NPAD = 100032;  // 1563 * 64
    float*          h    = (float*)alloc(NPAD * 64 * 4);
    float*          res  = (float*)alloc(NPAD * 64 * 4);   // residual; reused as v in readout
    unsigned short* hbh  = (unsigned short*)alloc(NPAD * 64 * 2);  // h bf16 hi
    unsigned short* hbl  = (unsigned short*)alloc(NPAD * 64 * 2);  // h bf16 lo
    unsigned short* zh   = (unsigned short*)alloc(NPAD * 64 * 2);  // agg/z bf16 hi
    unsigned short* zl   = (unsigned short*)alloc(NPAD * 64 * 2);  // agg/z bf16 lo
    int*   rowptr = (int*)alloc((size_t)(N + 1) * 4);
    int*   cnt    = (int*)alloc((size_t)N * 4);
    int*   col    = (int*)alloc((size_t)E * 4);
    float* stats  = (float*)alloc(9 * 512 * 4);   // 4 replicas x 128 per stage
    float* ss     = (float*)alloc(9 * 128 * 4);
    float* wks    = (float*)alloc(256 * 4);
    float* scores = (float*)alloc(NPAD * 4 * 4);
    int*   gs     = (int*)alloc((size_t)G * 4);
    int*   ge     = (int*)alloc((size_t)G * 4);
    float* pooled = (float*)alloc((size_t)G * 64 * 4);

    float* emb    = (float*)d_out;            // [G,64]
    float* logits = (float*)d_out + G * 64;   // [G,128]

    const int NB = (N + 63) / 64;  // 1563
    const float invN = 1.f / (float)N;

    // CSR build
    hipMemsetAsync(cnt, 0, (size_t)N * 4, stream);
    hipMemsetAsync(stats, 0, 9 * 512 * 4, stream);
    k_count<<<1024, 256, 0, stream>>>(dstv, cnt, E);
    k_scan<<<1, 1024, 0, stream>>>(cnt, rowptr, N);
    hipMemsetAsync(cnt, 0, (size_t)N * 4, stream);
    k_fill<<<1024, 256, 0, stream>>>(srcv, dstv, rowptr, cnt, col, E);

    // feature BN + projection
    k_xstats<<<512, 256, 0, stream>>>(x, stats, N);
    k_finalize<<<1, 64, 0, stream>>>(stats, fn_g, fn_b, ss, invN);
    k_proj<<<NB, 256, 0, stream>>>(x, ss, pW, pb, h, res, hbh, hbl, N);

    // 4 MPNN blocks x 2 GIN convs
    for (int m = 0; m < 4; ++m)
        for (int c = 0; c < 2; ++c) {
            int sidx = 1 + m * 2 + c;
            k_agg<<<1024, 256, 0, stream>>>(h, hbh, rowptr, col, zh, zl, N);
            k_mlp<<<NB, 256, 0, stream>>>(zh, zl,
                                          mlpW + (size_t)m * 3 * 64 * 64,
                                          mlpb + (size_t)m * 3 * 64,
                                          stats + (size_t)sidx * 512, N);
            k_finalize<<<1, 64, 0, stream>>>(stats + (size_t)sidx * 512, ngm + m * 64, nbt + m * 64,
                                             ss + (size_t)sidx * 128, invN);
            k_bnrelu<<<2048, 256, 0, stream>>>(
                (const ushort4*)zh, (const ushort4*)zl, ss + (size_t)sidx * 128,
                (float4*)h, (float4*)res, (ushort4*)hbh, (ushort4*)hbl,
                (c == 1) ? 1 : 0, N * 16);
        }

    // attention readout (v reuses res buffer — res is dead after last conv)
    float* vbuf = res;
    k_wks<<<1, 256, 0, stream>>>(Wk, seed, wks);
    k_vs<<<NB, 256, 0, stream>>>(hbh, hbl, Wv, wks, vbuf, scores, N);
    hipMemsetAsync(gs, 0x7f, (size_t)G * 4, stream);
    hipMemsetAsync(ge, 0, (size_t)G * 4, stream);
    k_bounds<<<512, 256, 0, stream>>>(batch, gs, ge, N);
    k_pool<<<G, 256, 0, stream>>>((const float4*)scores, vbuf, gs, ge, pooled, N);
    k_embed<<<(G + 63) / 64, 256, 0, stream>>>(pooled, Wo, emb, G);
    dim3 lg((G + 63) / 64, 2);
    k_logits<<<lg, 256, 0, stream>>>(emb, predW, predb, logits, G);
}

// Round 5
// 1187.832 us; speedup vs baseline: 5.3092x; 1.1904x over previous
//
#include <hip/hip_runtime.h>

#define LDA 68  // padded leading dim for 64-wide fp32 LDS tiles (small VALU GEMMs only)

typedef __attribute__((ext_vector_type(8))) short bf16x8;
typedef __attribute__((ext_vector_type(4))) float floatx4;

// bf16 helpers (RNE)
__device__ __forceinline__ unsigned short f2bf(float f)
{
    union { float f; unsigned int u; } v; v.f = f;
    unsigned int r = (v.u + 0x7fffu + ((v.u >> 16) & 1u)) >> 16;
    return (unsigned short)r;
}
__device__ __forceinline__ float bf2f(unsigned short b)
{
    union { unsigned int u; float f; } v; v.u = ((unsigned int)b) << 16;
    return v.f;
}

// acc += (Ah+Al) * (Bh+Bl), dropping Al*Bl  (~16-bit-mantissa GEMM)
#define MFMA3(accv, ah, al, bh, bl)                                              \
    accv = __builtin_amdgcn_mfma_f32_16x16x32_bf16(ah, bh, accv, 0, 0, 0);       \
    accv = __builtin_amdgcn_mfma_f32_16x16x32_bf16(al, bh, accv, 0, 0, 0);       \
    accv = __builtin_amdgcn_mfma_f32_16x16x32_bf16(ah, bl, accv, 0, 0, 0);

__device__ __forceinline__ void pack_pair(const float* f, bf16x8& hi, bf16x8& lo)
{
#pragma unroll
    for (int j = 0; j < 8; ++j) {
        unsigned short hb = f2bf(f[j]);
        hi[j] = (short)hb;
        lo[j] = (short)f2bf(f[j] - bf2f(hb));
    }
}

// stage fp32 W[64k][64n] -> LDS bf16 hi/lo, transposed+padded [n][72k] (B-frag friendly)
__device__ __forceinline__ void stage_wpair(const float* __restrict__ Wg,
                                            short* __restrict__ Wh, short* __restrict__ Wl, int t)
{
#pragma unroll
    for (int i = 0; i < 16; ++i) {
        int idx = i * 256 + t;
        int k = idx >> 6, n = idx & 63;
        float w = Wg[k * 64 + n];
        unsigned short hb = f2bf(w);
        Wh[n * 72 + k] = (short)hb;
        Wl[n * 72 + k] = (short)f2bf(w - bf2f(hb));
    }
}

// ---------------------------------------------------------------- small VALU GEMM helpers (k_embed/k_logits only)

__device__ __forceinline__ void stage_tile(const float* __restrict__ g, int base, int nrows,
                                           float* __restrict__ Ash, int t)
{
#pragma unroll
    for (int i = 0; i < 4; ++i) {
        int idx = i * 256 + t;
        int r = idx >> 4;
        int c = (idx & 15) << 2;
        float4 v = make_float4(0.f, 0.f, 0.f, 0.f);
        int row = base + r;
        if (row < nrows) v = *(const float4*)(g + (size_t)row * 64 + c);
        *(float4*)(Ash + r * LDA + c) = v;
    }
}

__device__ __forceinline__ void stage_w(const float* __restrict__ g, int ldg,
                                        float* __restrict__ Wsh, int t)
{
#pragma unroll
    for (int i = 0; i < 4; ++i) {
        int idx = i * 256 + t;
        int k = idx >> 4;
        int f = (idx & 15) << 2;
        *(float4*)(Wsh + k * 64 + f) = *(const float4*)(g + (size_t)k * ldg + f);
    }
}

__device__ __forceinline__ void gemm_tile(const float* __restrict__ Ash, const float* __restrict__ Wsh,
                                          float acc[4][4], int n0, int f0)
{
#pragma unroll
    for (int k0 = 0; k0 < 64; k0 += 4) {
        float a[4][4], w[4][4];
#pragma unroll
        for (int i = 0; i < 4; ++i) {
            float4 t4 = *(const float4*)(Ash + (n0 + i) * LDA + k0);
            a[i][0] = t4.x; a[i][1] = t4.y; a[i][2] = t4.z; a[i][3] = t4.w;
        }
#pragma unroll
        for (int k = 0; k < 4; ++k) {
            float4 t4 = *(const float4*)(Wsh + (k0 + k) * 64 + f0);
            w[k][0] = t4.x; w[k][1] = t4.y; w[k][2] = t4.z; w[k][3] = t4.w;
        }
#pragma unroll
        for (int i = 0; i < 4; ++i)
#pragma unroll
            for (int k = 0; k < 4; ++k)
#pragma unroll
                for (int j = 0; j < 4; ++j)
                    acc[i][j] = fmaf(a[i][k], w[k][j], acc[i][j]);
    }
}

// ---------------------------------------------------------------- CSR build

__global__ void k_count(const int* __restrict__ dst, int* __restrict__ cnt, int E)
{
    for (int e = blockIdx.x * 256 + threadIdx.x; e < E; e += gridDim.x * 256)
        atomicAdd(&cnt[dst[e]], 1);
}

// 3-phase multi-block exclusive scan (replaces the 163us single-block k_scan)
__global__ void k_scan1(const int* __restrict__ cnt, int* __restrict__ bsum, int n)
{
    __shared__ int red[256];
    int t = threadIdx.x;
    int i = blockIdx.x * 256 + t;
    red[t] = (i < n) ? cnt[i] : 0;
    __syncthreads();
    for (int off = 128; off; off >>= 1) {
        if (t < off) red[t] += red[t + off];
        __syncthreads();
    }
    if (t == 0) bsum[blockIdx.x] = red[0];
}

__global__ void k_scan2(const int* __restrict__ bsum, int* __restrict__ boff,
                        int nb, int* __restrict__ rowptrN)
{
    __shared__ int sc[512];
    int t = threadIdx.x;
    int v = (t < nb) ? bsum[t] : 0;
    sc[t] = v;
    __syncthreads();
    for (int off = 1; off < 512; off <<= 1) {
        int u = (t >= off) ? sc[t - off] : 0;
        __syncthreads();
        sc[t] += u;
        __syncthreads();
    }
    if (t < nb) boff[t] = sc[t] - v;
    if (t == nb - 1) *rowptrN = sc[t];
}

// also re-zeros cnt so k_fill can use it as cursor without a memset
__global__ void k_scan3(int* __restrict__ cnt, const int* __restrict__ boff,
                        int* __restrict__ rowptr, int n)
{
    __shared__ int sc[256];
    int t = threadIdx.x;
    int i = blockIdx.x * 256 + t;
    int v = (i < n) ? cnt[i] : 0;
    sc[t] = v;
    __syncthreads();
    for (int off = 1; off < 256; off <<= 1) {
        int u = (t >= off) ? sc[t - off] : 0;
        __syncthreads();
        sc[t] += u;
        __syncthreads();
    }
    if (i < n) {
        rowptr[i] = boff[blockIdx.x] + sc[t] - v;
        cnt[i] = 0;
    }
}

__global__ void k_fill(const int* __restrict__ src, const int* __restrict__ dst,
                       const int* __restrict__ rowptr, int* __restrict__ cursor,
                       int* __restrict__ col, int E)
{
    for (int e = blockIdx.x * 256 + threadIdx.x; e < E; e += gridDim.x * 256) {
        int d = dst[e];
        int p = atomicAdd(&cursor[d], 1);
        col[rowptr[d] + p] = src[e];
    }
}

// ---------------------------------------------------------------- feature BN stats (4-way replicated atomics)

__global__ void k_xstats(const float* __restrict__ x, float* __restrict__ stats, int N)
{
    __shared__ float rs[256], rq[256];
    int t = threadIdx.x;
    int f = t & 63, rg = t >> 6;
    float s = 0.f, q = 0.f;
    for (int r = blockIdx.x * 4 + rg; r < N; r += gridDim.x * 4) {
        float v = x[(size_t)r * 64 + f];
        s += v; q += v * v;
    }
    rs[rg * 64 + f] = s; rq[rg * 64 + f] = q;
    __syncthreads();
    if (t < 64) {
        float ts = rs[t] + rs[64 + t] + rs[128 + t] + rs[192 + t];
        float tq = rq[t] + rq[64 + t] + rq[128 + t] + rq[192 + t];
        int rep = (blockIdx.x & 3) * 128;
        atomicAdd(&stats[rep + t], ts);
        atomicAdd(&stats[rep + 64 + t], tq);
    }
}

// compute per-feature scale/shift from 4-replica stats into LDS[128]
__device__ __forceinline__ void finalize_lds(const float* __restrict__ stats,
                                             const float* __restrict__ gamma,
                                             const float* __restrict__ beta,
                                             float* __restrict__ SS, int t, float invN)
{
    if (t < 64) {
        float su = stats[t] + stats[128 + t] + stats[256 + t] + stats[384 + t];
        float qu = stats[64 + t] + stats[192 + t] + stats[320 + t] + stats[448 + t];
        float mu = su * invN;
        float var = qu * invN - mu * mu;
        float sc = gamma[t] * rsqrtf(var + 1e-5f);
        SS[t] = sc;
        SS[64 + t] = beta[t] - mu * sc;
    }
}

// ---------------------------------------------------------------- input projection (MFMA, inline BN finalize)

__global__ void __launch_bounds__(256, 4)
k_proj(const float* __restrict__ x, const float* __restrict__ stats,
       const float* __restrict__ fn_g, const float* __restrict__ fn_b,
       const float* __restrict__ W, const float* __restrict__ b,
       float* __restrict__ res,
       unsigned short* __restrict__ hbh, unsigned short* __restrict__ hbl,
       int N, float invN)
{
    __shared__ short Wh[64 * 72], Wl[64 * 72];
    __shared__ float ScSh[128];
    __shared__ float BiasSh[64];
    int t = threadIdx.x;
    int wave = t >> 6, lane = t & 63;
    int m = lane & 15, qd = lane >> 4;
    int base = blockIdx.x * 64;
    int nodeA = base + wave * 16 + m;

    finalize_lds(stats, fn_g, fn_b, ScSh, t, invN);
    if (t < 64) BiasSh[t] = b[t];
    stage_wpair(W, Wh, Wl, t);
    __syncthreads();

    int rowc = min(nodeA, N - 1);
    bf16x8 ah[2], al[2];
#pragma unroll
    for (int kc = 0; kc < 2; ++kc) {
        floatx4 x0 = *(const floatx4*)(x + (size_t)rowc * 64 + kc * 32 + qd * 8);
        floatx4 x1 = *(const floatx4*)(x + (size_t)rowc * 64 + kc * 32 + qd * 8 + 4);
        float av[8];
#pragma unroll
        for (int j = 0; j < 8; ++j) {
            int k = kc * 32 + qd * 8 + j;
            float xv = (j < 4) ? x0[j] : x1[j - 4];
            av[j] = xv * ScSh[k] + ScSh[64 + k];
        }
        pack_pair(av, ah[kc], al[kc]);
    }

    floatx4 acc[4];
#pragma unroll
    for (int tt = 0; tt < 4; ++tt) {
        float bv = BiasSh[tt * 16 + m];
        acc[tt] = (floatx4){bv, bv, bv, bv};
    }
#pragma unroll
    for (int kc = 0; kc < 2; ++kc)
#pragma unroll
        for (int tt = 0; tt < 4; ++tt) {
            bf16x8 bh = *(const bf16x8*)(Wh + (tt * 16 + m) * 72 + kc * 32 + qd * 8);
            bf16x8 bl = *(const bf16x8*)(Wl + (tt * 16 + m) * 72 + kc * 32 + qd * 8);
            MFMA3(acc[tt], ah[kc], al[kc], bh, bl);
        }

#pragma unroll
    for (int tt = 0; tt < 4; ++tt)
#pragma unroll
        for (int r = 0; r < 4; ++r) {
            int node = base + wave * 16 + qd * 4 + r;
            if (node < N) {
                int col = tt * 16 + m;
                float v = fmaxf(acc[tt][r], 0.f);
                res[(size_t)node * 64 + col] = v;
                unsigned short hb = f2bf(v);
                hbh[(size_t)node * 64 + col] = hb;
                hbl[(size_t)node * 64 + col] = f2bf(v - bf2f(hb));
            }
        }
}

// ---------------------------------------------------------------- fused GIN conv: gather + 3-layer MFMA MLP + BN stats
// Gather phase: lane = feature, each wave aggregates its 16 A-rows into LDS (fp32).
// MLP: 16x16x32 bf16-pair MFMA, inter-layer transpose through the same LDS tile.

__global__ void __launch_bounds__(256, 4)
k_conv(const unsigned short* __restrict__ hbh, const unsigned short* __restrict__ hbl,
       const int* __restrict__ rowptr, const int* __restrict__ col,
       const float* __restrict__ W3, const float* __restrict__ b3,
       unsigned short* __restrict__ zh, unsigned short* __restrict__ zl,
       float* __restrict__ stats, int N)
{
    __shared__ short Wh[64 * 72], Wl[64 * 72];
    __shared__ float Aint[64 * 68];
    __shared__ float BiasSh[192];
    int t = threadIdx.x;
    int wave = t >> 6, lane = t & 63;
    int m = lane & 15, qd = lane >> 4;
    int base = blockIdx.x * 64;
    float* Aw = Aint + wave * 1088;  // 16 rows x 68

    if (t < 192) BiasSh[t] = b3[t];
    stage_wpair(W3, Wh, Wl, t);

    // ---- gather: self (hi+lo pair ~ fp32) + bf16 neighbor sum
#pragma unroll 1
    for (int i = 0; i < 16; ++i) {
        int node = base + wave * 16 + i;
        float a = 0.f;
        if (node < N) {
            a = bf2f(hbh[(size_t)node * 64 + lane]) + bf2f(hbl[(size_t)node * 64 + lane]);
            int e0 = rowptr[node], e1 = rowptr[node + 1];
            int e = e0;
            for (; e + 8 <= e1; e += 8) {
                int s0 = col[e + 0], s1 = col[e + 1], s2 = col[e + 2], s3 = col[e + 3];
                int s4 = col[e + 4], s5 = col[e + 5], s6 = col[e + 6], s7 = col[e + 7];
                float v0 = bf2f(hbh[(size_t)s0 * 64 + lane]);
                float v1 = bf2f(hbh[(size_t)s1 * 64 + lane]);
                float v2 = bf2f(hbh[(size_t)s2 * 64 + lane]);
                float v3 = bf2f(hbh[(size_t)s3 * 64 + lane]);
                float v4 = bf2f(hbh[(size_t)s4 * 64 + lane]);
                float v5 = bf2f(hbh[(size_t)s5 * 64 + lane]);
                float v6 = bf2f(hbh[(size_t)s6 * 64 + lane]);
                float v7 = bf2f(hbh[(size_t)s7 * 64 + lane]);
                a += ((v0 + v1) + (v2 + v3)) + ((v4 + v5) + (v6 + v7));
            }
            if (e + 4 <= e1) {
                int s0 = col[e + 0], s1 = col[e + 1], s2 = col[e + 2], s3 = col[e + 3];
                a += (bf2f(hbh[(size_t)s0 * 64 + lane]) + bf2f(hbh[(size_t)s1 * 64 + lane]))
                   + (bf2f(hbh[(size_t)s2 * 64 + lane]) + bf2f(hbh[(size_t)s3 * 64 + lane]));
                e += 4;
            }
            if (e + 2 <= e1) {
                a += bf2f(hbh[(size_t)col[e] * 64 + lane]) + bf2f(hbh[(size_t)col[e + 1] * 64 + lane]);
                e += 2;
            }
            if (e < e1) a += bf2f(hbh[(size_t)col[e] * 64 + lane]);
        }
        Aw[i * 68 + lane] = a;
    }
    __syncthreads();

    floatx4 acc[4];

    // -------- linear 1 + relu
#pragma unroll
    for (int tt = 0; tt < 4; ++tt) {
        float bv = BiasSh[tt * 16 + m];
        acc[tt] = (floatx4){bv, bv, bv, bv};
    }
#pragma unroll
    for (int kc = 0; kc < 2; ++kc) {
        floatx4 x0 = *(const floatx4*)(Aw + m * 68 + kc * 32 + qd * 8);
        floatx4 x1 = *(const floatx4*)(Aw + m * 68 + kc * 32 + qd * 8 + 4);
        float av[8];
#pragma unroll
        for (int j = 0; j < 8; ++j) av[j] = (j < 4) ? x0[j] : x1[j - 4];
        bf16x8 ah, al;
        pack_pair(av, ah, al);
#pragma unroll
        for (int tt = 0; tt < 4; ++tt) {
            bf16x8 bh = *(const bf16x8*)(Wh + (tt * 16 + m) * 72 + kc * 32 + qd * 8);
            bf16x8 bl = *(const bf16x8*)(Wl + (tt * 16 + m) * 72 + kc * 32 + qd * 8);
            MFMA3(acc[tt], ah, al, bh, bl);
        }
    }
#pragma unroll
    for (int tt = 0; tt < 4; ++tt)
#pragma unroll
        for (int r = 0; r < 4; ++r)
            Aw[(qd * 4 + r) * 68 + tt * 16 + m] = fmaxf(acc[tt][r], 0.f);
    __syncthreads();
    stage_wpair(W3 + 4096, Wh, Wl, t);
    __syncthreads();

    // -------- linear 2 + relu
#pragma unroll
    for (int tt = 0; tt < 4; ++tt) {
        float bv = BiasSh[64 + tt * 16 + m];
        acc[tt] = (floatx4){bv, bv, bv, bv};
    }
#pragma unroll
    for (int kc = 0; kc < 2; ++kc) {
        floatx4 x0 = *(const floatx4*)(Aw + m * 68 + kc * 32 + qd * 8);
        floatx4 x1 = *(const floatx4*)(Aw + m * 68 + kc * 32 + qd * 8 + 4);
        float av[8];
#pragma unroll
        for (int j = 0; j < 8; ++j) av[j] = (j < 4) ? x0[j] : x1[j - 4];
        bf16x8 ah, al;
        pack_pair(av, ah, al);
#pragma unroll
        for (int tt = 0; tt < 4; ++tt) {
            bf16x8 bh = *(const bf16x8*)(Wh + (tt * 16 + m) * 72 + kc * 32 + qd * 8);
            bf16x8 bl = *(const bf16x8*)(Wl + (tt * 16 + m) * 72 + kc * 32 + qd * 8);
            MFMA3(acc[tt], ah, al, bh, bl);
        }
    }
#pragma unroll
    for (int tt = 0; tt < 4; ++tt)
#pragma unroll
        for (int r = 0; r < 4; ++r)
            Aw[(qd * 4 + r) * 68 + tt * 16 + m] = fmaxf(acc[tt][r], 0.f);
    __syncthreads();
    stage_wpair(W3 + 8192, Wh, Wl, t);
    __syncthreads();

    // -------- linear 3 (no relu)
#pragma unroll
    for (int tt = 0; tt < 4; ++tt) {
        float bv = BiasSh[128 + tt * 16 + m];
        acc[tt] = (floatx4){bv, bv, bv, bv};
    }
#pragma unroll
    for (int kc = 0; kc < 2; ++kc) {
        floatx4 x0 = *(const floatx4*)(Aw + m * 68 + kc * 32 + qd * 8);
        floatx4 x1 = *(const floatx4*)(Aw + m * 68 + kc * 32 + qd * 8 + 4);
        float av[8];
#pragma unroll
        for (int j = 0; j < 8; ++j) av[j] = (j < 4) ? x0[j] : x1[j - 4];
        bf16x8 ah, al;
        pack_pair(av, ah, al);
#pragma unroll
        for (int tt = 0; tt < 4; ++tt) {
            bf16x8 bh = *(const bf16x8*)(Wh + (tt * 16 + m) * 72 + kc * 32 + qd * 8);
            bf16x8 bl = *(const bf16x8*)(Wl + (tt * 16 + m) * 72 + kc * 32 + qd * 8);
            MFMA3(acc[tt], ah, al, bh, bl);
        }
    }

    // store pre-BN z as bf16 pair
#pragma unroll
    for (int tt = 0; tt < 4; ++tt)
#pragma unroll
        for (int r = 0; r < 4; ++r) {
            int node = base + wave * 16 + qd * 4 + r;
            if (node < N) {
                int colg = tt * 16 + m;
                float v = acc[tt][r];
                unsigned short hb = f2bf(v);
                zh[(size_t)node * 64 + colg] = hb;
                zl[(size_t)node * 64 + colg] = f2bf(v - bf2f(hb));
            }
        }

    // BN partial stats from fp32 accumulators (Aint reused as scratch: 64*68 >= 4096 floats)
    __syncthreads();
    float* SW = Aint;
#pragma unroll
    for (int tt = 0; tt < 4; ++tt) {
        float s = 0.f, q = 0.f;
#pragma unroll
        for (int r = 0; r < 4; ++r) {
            int node = base + wave * 16 + qd * 4 + r;
            float v = (node < N) ? acc[tt][r] : 0.f;
            s += v; q += v * v;
        }
        SW[(tt * 16 + m) * 16 + wave * 4 + qd] = s;
        SW[2048 + (tt * 16 + m) * 16 + wave * 4 + qd] = q;
    }
    __syncthreads();
    if (t < 64) {
        float s = 0.f, q = 0.f;
#pragma unroll
        for (int i = 0; i < 16; ++i) { s += SW[t * 16 + i]; q += SW[2048 + t * 16 + i]; }
        int rep = (blockIdx.x & 3) * 128;
        atomicAdd(&stats[rep + t], s);
        atomicAdd(&stats[rep + 64 + t], q);
    }
}

// ---------------------------------------------------------------- BN apply + relu (+ residual), inline finalize

__global__ void k_bnrelu(const ushort4* __restrict__ zh4, const ushort4* __restrict__ zl4,
                         const float* __restrict__ stats, const float* __restrict__ gamma,
                         const float* __restrict__ beta,
                         float4* __restrict__ res4,
                         ushort4* __restrict__ hbh4, ushort4* __restrict__ hbl4,
                         int second, int total4, float invN)
{
    __shared__ float SS[128];
    int t = threadIdx.x;
    finalize_lds(stats, gamma, beta, SS, t, invN);
    __syncthreads();
    for (int idx = blockIdx.x * 256 + t; idx < total4; idx += gridDim.x * 256) {
        int c = (idx & 15) << 2;
        ushort4 zh = zh4[idx], zl = zl4[idx];
        float4 v;
        v.x = bf2f(zh.x) + bf2f(zl.x);
        v.y = bf2f(zh.y) + bf2f(zl.y);
        v.z = bf2f(zh.z) + bf2f(zl.z);
        v.w = bf2f(zh.w) + bf2f(zl.w);
        v.x = fmaxf(v.x * SS[c + 0] + SS[64 + c + 0], 0.f);
        v.y = fmaxf(v.y * SS[c + 1] + SS[64 + c + 1], 0.f);
        v.z = fmaxf(v.z * SS[c + 2] + SS[64 + c + 2], 0.f);
        v.w = fmaxf(v.w * SS[c + 3] + SS[64 + c + 3], 0.f);
        if (second) {
            float4 r = res4[idx];
            v.x += r.x; v.y += r.y; v.z += r.z; v.w += r.w;
            res4[idx] = v;
        }
        ushort4 ph, pl;
        ph.x = f2bf(v.x); pl.x = f2bf(v.x - bf2f(ph.x));
        ph.y = f2bf(v.y); pl.y = f2bf(v.y - bf2f(ph.y));
        ph.z = f2bf(v.z); pl.z = f2bf(v.z - bf2f(ph.z));
        ph.w = f2bf(v.w); pl.w = f2bf(v.w - bf2f(ph.w));
        hbh4[idx] = ph; hbl4[idx] = pl;
    }
}

// ---------------------------------------------------------------- attention readout

__global__ void k_wks(const float* __restrict__ Wk, const float* __restrict__ seed,
                      float* __restrict__ wks)
{
    int t = threadIdx.x;  // 256
    int i = t >> 2, hh = t & 3;
    float s = 0.f;
#pragma unroll
    for (int d = 0; d < 16; ++d) s += Wk[i * 64 + hh * 16 + d] * seed[hh * 16 + d];
    wks[i * 4 + hh] = s * 0.25f;  // 1/sqrt(16)
}

// v = h @ Wv (MFMA, pair) and scores = h @ wks (extra 16-wide tile, cols 0-3 live)
__global__ void __launch_bounds__(256, 4)
k_vs(const unsigned short* __restrict__ hbh, const unsigned short* __restrict__ hbl,
     const float* __restrict__ Wv, const float* __restrict__ wksg,
     float* __restrict__ v, float* __restrict__ scores, int N)
{
    __shared__ short Wh[64 * 72], Wl[64 * 72];
    __shared__ short Sh[16 * 72], Sl[16 * 72];
    int t = threadIdx.x;
    int wave = t >> 6, lane = t & 63;
    int m = lane & 15, qd = lane >> 4;
    int base = blockIdx.x * 64;
    int nodeA = base + wave * 16 + m;

    stage_wpair(Wv, Wh, Wl, t);
#pragma unroll
    for (int i = 0; i < 4; ++i) {
        int idx = i * 256 + t;
        int k = idx >> 4, n = idx & 15;
        float wv = (n < 4) ? wksg[k * 4 + n] : 0.f;
        unsigned short hb = f2bf(wv);
        Sh[n * 72 + k] = (short)hb;
        Sl[n * 72 + k] = (short)f2bf(wv - bf2f(hb));
    }

    bf16x8 ah[2], al[2];
#pragma unroll
    for (int kc = 0; kc < 2; ++kc) {
        ah[kc] = *(const bf16x8*)(hbh + (size_t)nodeA * 64 + kc * 32 + qd * 8);
        al[kc] = *(const bf16x8*)(hbl + (size_t)nodeA * 64 + kc * 32 + qd * 8);
    }
    __syncthreads();

    floatx4 acc[5] = {};
#pragma unroll
    for (int kc = 0; kc < 2; ++kc) {
#pragma unroll
        for (int tt = 0; tt < 4; ++tt) {
            bf16x8 bh = *(const bf16x8*)(Wh + (tt * 16 + m) * 72 + kc * 32 + qd * 8);
            bf16x8 bl = *(const bf16x8*)(Wl + (tt * 16 + m) * 72 + kc * 32 + qd * 8);
            MFMA3(acc[tt], ah[kc], al[kc], bh, bl);
        }
        bf16x8 sh = *(const bf16x8*)(Sh + m * 72 + kc * 32 + qd * 8);
        bf16x8 sl = *(const bf16x8*)(Sl + m * 72 + kc * 32 + qd * 8);
        MFMA3(acc[4], ah[kc], al[kc], sh, sl);
    }

#pragma unroll
    for (int tt = 0; tt < 4; ++tt)
#pragma unroll
        for (int r = 0; r < 4; ++r) {
            int node = base + wave * 16 + qd * 4 + r;
            if (node < N)
                v[(size_t)node * 64 + tt * 16 + m] = acc[tt][r];
        }
    if (m < 4) {
#pragma unroll
        for (int r = 0; r < 4; ++r) {
            int node = base + wave * 16 + qd * 4 + r;
            if (node < N) scores[(size_t)node * 4 + m] = acc[4][r];
        }
    }
}

// per-graph softmax pooling; graph bounds via binary search over sorted batch
__global__ void k_pool(const float4* __restrict__ scores4, const float* __restrict__ v,
                       const int* __restrict__ batch, float* __restrict__ pooled, int N)
{
    int g = blockIdx.x;
    int t = threadIdx.x;
    __shared__ int sb[2];
    __shared__ float4 rmax[256];
    __shared__ float racc[256];
    __shared__ float resum[16];
    if (t < 2) {
        int target = g + t;
        int lo = 0, hi = N;
        while (lo < hi) {
            int mid = (lo + hi) >> 1;
            if (batch[mid] < target) lo = mid + 1; else hi = mid;
        }
        sb[t] = lo;
    }
    __syncthreads();
    int s = sb[0], e = sb[1];
    if (s >= e) {
        if (t < 64) pooled[g * 64 + t] = 0.f;
        return;
    }
    float4 m = make_float4(-1e30f, -1e30f, -1e30f, -1e30f);
    for (int i = s + t; i < e; i += 256) {
        float4 sc = scores4[i];
        m.x = fmaxf(m.x, sc.x); m.y = fmaxf(m.y, sc.y);
        m.z = fmaxf(m.z, sc.z); m.w = fmaxf(m.w, sc.w);
    }
    rmax[t] = m;
    __syncthreads();
    for (int off = 128; off; off >>= 1) {
        if (t < off) {
            float4 a = rmax[t], b = rmax[t + off];
            a.x = fmaxf(a.x, b.x); a.y = fmaxf(a.y, b.y);
            a.z = fmaxf(a.z, b.z); a.w = fmaxf(a.w, b.w);
            rmax[t] = a;
        }
        __syncthreads();
    }
    float4 smax = rmax[0];
    int rg = t >> 6, f = t & 63, hh = f >> 4;
    float mx = (hh == 0) ? smax.x : ((hh == 1) ? smax.y : ((hh == 2) ? smax.z : smax.w));
    float acc = 0.f, es = 0.f;
    for (int i = s + rg; i < e; i += 4) {
        float4 sc = scores4[i];
        float scl = (hh == 0) ? sc.x : ((hh == 1) ? sc.y : ((hh == 2) ? sc.z : sc.w));
        float ev = __expf(scl - mx);
        acc += ev * v[(size_t)i * 64 + f];
        if ((f & 15) == 0) es += ev;
    }
    racc[rg * 64 + f] = acc;
    if ((f & 15) == 0) resum[rg * 4 + hh] = es;
    __syncthreads();
    if (t < 64) {
        float tot = racc[t] + racc[64 + t] + racc[128 + t] + racc[192 + t];
        int h2 = t >> 4;
        float den = resum[h2] + resum[4 + h2] + resum[8 + h2] + resum[12 + h2];
        pooled[g * 64 + t] = tot / den;
    }
}

__global__ void k_embed(const float* __restrict__ pooled, const float* __restrict__ Wo,
                        float* __restrict__ out, int G)
{
    __shared__ __align__(16) float Ash[64 * LDA];
    __shared__ __align__(16) float Wsh[64 * 64];
    int t = threadIdx.x;
    int base = blockIdx.x * 64;
    stage_tile(pooled, base, G, Ash, t);
    stage_w(Wo, 64, Wsh, t);
    __syncthreads();
    int n0 = (t >> 4) << 2, f0 = (t & 15) << 2;
    float acc[4][4] = {};
    gemm_tile(Ash, Wsh, acc, n0, f0);
#pragma unroll
    for (int i = 0; i < 4; ++i) {
        int row = base + n0 + i;
        if (row < G)
            *(float4*)(out + (size_t)row * 64 + f0) =
                make_float4(acc[i][0], acc[i][1], acc[i][2], acc[i][3]);
    }
}

__global__ void k_logits(const float* __restrict__ embed, const float* __restrict__ W,
                         const float* __restrict__ b, float* __restrict__ out, int G)
{
    __shared__ __align__(16) float Ash[64 * LDA];
    __shared__ __align__(16) float Wsh[64 * 64];
    int t = threadIdx.x;
    int base = blockIdx.x * 64;
    int co = blockIdx.y * 64;
    stage_tile(embed, base, G, Ash, t);
#pragma unroll
    for (int i = 0; i < 4; ++i) {
        int idx = i * 256 + t;
        int k = idx >> 4;
        int f = (idx & 15) << 2;
        *(float4*)(Wsh + k * 64 + f) = *(const float4*)(W + (size_t)k * 128 + co + f);
    }
    __syncthreads();
    int n0 = (t >> 4) << 2, f0 = (t & 15) << 2;
    float acc[4][4];
    float4 b4 = *(const float4*)(b + co + f0);
#pragma unroll
    for (int i = 0; i < 4; ++i) { acc[i][0] = b4.x; acc[i][1] = b4.y; acc[i][2] = b4.z; acc[i][3] = b4.w; }
    gemm_tile(Ash, Wsh, acc, n0, f0);
#pragma unroll
    for (int i = 0; i < 4; ++i) {
        int row = base + n0 + i;
        if (row < G)
            *(float4*)(out + (size_t)row * 128 + co + f0) =
                make_float4(acc[i][0], acc[i][1], acc[i][2], acc[i][3]);
    }
}

// ---------------------------------------------------------------- launch

extern "C" void kernel_launch(void* const* d_in, const int* in_sizes, int n_in,
                              void* d_out, int out_size, void* d_ws, size_t ws_size,
                              hipStream_t stream)
{
    const float* x     = (const float*)d_in[0];
    const int*   eidx  = (const int*)d_in[1];
    const int*   batch = (const int*)d_in[2];
    const float* fn_g  = (const float*)d_in[3];
    const float* fn_b  = (const float*)d_in[4];
    const float* pW    = (const float*)d_in[5];
    const float* pb    = (const float*)d_in[6];
    const float* mlpW  = (const float*)d_in[7];
    const float* mlpb  = (const float*)d_in[8];
    const float* ngm   = (const float*)d_in[9];
    const float* nbt   = (const float*)d_in[10];
    const float* seed  = (const float*)d_in[11];
    const float* Wk    = (const float*)d_in[12];
    const float* Wv    = (const float*)d_in[13];
    const float* Wo    = (const float*)d_in[14];
    const float* predW = (const float*)d_in[15];
    const float* predb = (const float*)d_in[16];

    const int N = 100000, E = 1000000, G = 1000;
    const int* srcv = eidx;
    const int* dstv = eidx + E;

    char* w = (char*)d_ws;
    auto alloc = [&](size_t bytes) {
        char* p = w;
        w += (bytes + 255) & ~(size_t)255;
        return p;
    };
    const size_t NPAD = 100032;  // 1563 * 64
    float*          res  = (float*)alloc(NPAD * 64 * 4);   // residual; reused as v in readout
    unsigned short* hbh  = (unsigned short*)alloc(NPAD * 64 * 2);  // h bf16 hi
    unsigned short* hbl  = (unsigned short*)alloc(NPAD * 64 * 2);  // h bf16 lo
    unsigned short* zh   = (unsigned short*)alloc(NPAD * 64 * 2);  // z bf16 hi
    unsigned short* zl   = (unsigned short*)alloc(NPAD * 64 * 2);  // z bf16 lo
    int*   rowptr = (int*)alloc((size_t)(N + 1) * 4);
    int*   cnt    = (int*)alloc((size_t)N * 4);
    int*   col    = (int*)alloc((size_t)E * 4);
    int*   bsum   = (int*)alloc(512 * 4);
    int*   boff   = (int*)alloc(512 * 4);
    float* stats  = (float*)alloc(9 * 512 * 4);   // 4 replicas x 128 per stage
    float* wks    = (float*)alloc(256 * 4);
    float* scores = (float*)alloc(NPAD * 4 * 4);
    float* pooled = (float*)alloc((size_t)G * 64 * 4);

    float* emb    = (float*)d_out;            // [G,64]
    float* logits = (float*)d_out + G * 64;   // [G,128]

    const int NB = (N + 63) / 64;     // 1563
    const int NBS = (N + 255) / 256;  // 391
    const float invN = 1.f / (float)N;

    // CSR build (multi-block scan; scan3 re-zeros cnt for use as fill cursor)
    hipMemsetAsync(cnt, 0, (size_t)N * 4, stream);
    hipMemsetAsync(stats, 0, 9 * 512 * 4, stream);
    k_count<<<1024, 256, 0, stream>>>(dstv, cnt, E);
    k_scan1<<<NBS, 256, 0, stream>>>(cnt, bsum, N);
    k_scan2<<<1, 512, 0, stream>>>(bsum, boff, NBS, rowptr + N);
    k_scan3<<<NBS, 256, 0, stream>>>(cnt, boff, rowptr, N);
    k_fill<<<1024, 256, 0, stream>>>(srcv, dstv, rowptr, cnt, col, E);

    // feature BN + projection (finalize inlined in k_proj)
    k_xstats<<<512, 256, 0, stream>>>(x, stats, N);
    k_proj<<<NB, 256, 0, stream>>>(x, stats, fn_g, fn_b, pW, pb, res, hbh, hbl, N, invN);

    // 4 MPNN blocks x 2 GIN convs (gather fused into conv; finalize inlined in bnrelu)
    for (int m = 0; m < 4; ++m)
        for (int c = 0; c < 2; ++c) {
            int sidx = 1 + m * 2 + c;
            k_conv<<<NB, 256, 0, stream>>>(hbh, hbl, rowptr, col,
                                           mlpW + (size_t)m * 3 * 64 * 64,
                                           mlpb + (size_t)m * 3 * 64,
                                           zh, zl, stats + (size_t)sidx * 512, N);
            k_bnrelu<<<2048, 256, 0, stream>>>(
                (const ushort4*)zh, (const ushort4*)zl,
                stats + (size_t)sidx * 512, ngm + m * 64, nbt + m * 64,
                (float4*)res, (ushort4*)hbh, (ushort4*)hbl,
                (c == 1) ? 1 : 0, N * 16, invN);
        }

    // attention readout (v reuses res buffer — res is dead after last conv)
    float* vbuf = res;
    k_wks<<<1, 256, 0, stream>>>(Wk, seed, wks);
    k_vs<<<NB, 256, 0, stream>>>(hbh, hbl, Wv, wks, vbuf, scores, N);
    k_pool<<<G, 256, 0, stream>>>((const float4*)scores, vbuf, batch, pooled, N);
    k_embed<<<(G + 63) / 64, 256, 0, stream>>>(pooled, Wo, emb, G);
    dim3 lg((G + 63) / 64, 2);
    k_logits<<<lg, 256, 0, stream>>>(emb, predW, predb, logits, G);
}